// Round 5
// baseline (1075.112 us; speedup 1.0000x reference)
//
#include <hip/hip_runtime.h>
#include <hip/hip_bf16.h>
#include <hip/hip_fp16.h>

#define BD 4
#define SS 4096
#define DD 1024
#define RTOT (BD*SS)   // 16384 total rows

typedef _Float16 f16;
typedef __attribute__((ext_vector_type(8))) _Float16 f16x8;
typedef __attribute__((ext_vector_type(8))) short bf16x8;
typedef __attribute__((ext_vector_type(4))) float f32x4;

static __device__ __forceinline__ unsigned short f2bf(float f) {
  unsigned int u = __float_as_uint(f);
  u += 0x7fff + ((u >> 16) & 1);   // RNE
  return (unsigned short)(u >> 16);
}
static __device__ __forceinline__ float bf2f(unsigned short h) {
  return __uint_as_float(((unsigned int)h) << 16);
}
static __device__ __forceinline__ unsigned short f2h(float f) {
  f16 h = (f16)f;
  return __builtin_bit_cast(unsigned short, h);
}

// async global->LDS, 16B/lane, wave-uniform LDS base + lane*16
static __device__ __forceinline__ void gload16(const void* g, void* l) {
  __builtin_amdgcn_global_load_lds(
      (const __attribute__((address_space(1))) unsigned int*)g,
      (__attribute__((address_space(3))) unsigned int*)l, 16, 0, 0);
}

// ---------------- split W into hi/lo bf16 ----------------
__global__ void split_w_kernel(const float* __restrict__ W,
                               unsigned short* __restrict__ Whi,
                               unsigned short* __restrict__ Wlo) {
  int i = (blockIdx.x * 256 + threadIdx.x) * 4;
  float4 x = *reinterpret_cast<const float4*>(W + i);
  ushort4 h, l;
  h.x = f2bf(x.x); l.x = f2bf(x.x - bf2f(h.x));
  h.y = f2bf(x.y); l.y = f2bf(x.y - bf2f(h.y));
  h.z = f2bf(x.z); l.z = f2bf(x.z - bf2f(h.z));
  h.w = f2bf(x.w); l.w = f2bf(x.w - bf2f(h.w));
  *reinterpret_cast<ushort4*>(Whi + i) = h;
  *reinterpret_cast<ushort4*>(Wlo + i) = l;
}

// ---------------- q+k projection (fused z=2): P = X W^T + b, bf16 3-term ----------------
// dbuf + T14 async-STAGE split: loads issued before compute, writes after.
__global__ __launch_bounds__(256)
void proj_qk(const float* __restrict__ Xq, const float* __restrict__ Xk,
             const unsigned short* __restrict__ Wh,
             const unsigned short* __restrict__ Wl,
             const float* __restrict__ bias,
             unsigned short* __restrict__ Oqh, unsigned short* __restrict__ Oql,
             unsigned short* __restrict__ Okh, unsigned short* __restrict__ Okl)
{
  __shared__ unsigned short Ah[2][128][40], Al[2][128][40];   // 40KB
  __shared__ unsigned short Bh[2][128][32], Bl[2][128][32];   // 32KB
  const int tid = threadIdx.x, lane = tid & 63, wid = tid >> 6;
  const int m0 = blockIdx.x * 128, n0 = blockIdx.y * 128;
  const int wm = (wid >> 1) * 64, wn = (wid & 1) * 64;

  const float* X = blockIdx.z ? Xk : Xq;
  unsigned short* Ohi = blockIdx.z ? Okh : Oqh;
  unsigned short* Olo = blockIdx.z ? Okl : Oql;

  // per-thread stage coords (4 A-rounds, 2 B-rounds)
  const int ar[4] = { (0*256+tid) >> 3, (1*256+tid) >> 3, (2*256+tid) >> 3, (3*256+tid) >> 3 };
  const int ac = (tid & 7) * 4;
  const int b0r = tid >> 2, b0c = (tid & 3) * 8;
  const int b1r = 64 + (tid >> 2);

  f32x4 acc[4][4] = {};
  float4 axr[4];

#define PQK_BLOAD(buf, k0) do { \
    gload16(Wh + (size_t)(n0 + b0r) * DD + (k0) + b0c, &Bh[buf][0][0] + (size_t)tid * 8); \
    gload16(Wl + (size_t)(n0 + b0r) * DD + (k0) + b0c, &Bl[buf][0][0] + (size_t)tid * 8); \
    gload16(Wh + (size_t)(n0 + b1r) * DD + (k0) + b0c, &Bh[buf][0][0] + (size_t)(256 + tid) * 8); \
    gload16(Wl + (size_t)(n0 + b1r) * DD + (k0) + b0c, &Bl[buf][0][0] + (size_t)(256 + tid) * 8); \
  } while (0)

#define PQK_ALOAD(k0) do { \
    _Pragma("unroll") \
    for (int rnd = 0; rnd < 4; ++rnd) \
      axr[rnd] = *reinterpret_cast<const float4*>(X + (size_t)(m0 + ar[rnd]) * DD + (k0) + ac); \
  } while (0)

#define PQK_AWRITE(buf) do { \
    _Pragma("unroll") \
    for (int rnd = 0; rnd < 4; ++rnd) { \
      ushort4 h, l; \
      h.x = f2bf(axr[rnd].x); l.x = f2bf(axr[rnd].x - bf2f(h.x)); \
      h.y = f2bf(axr[rnd].y); l.y = f2bf(axr[rnd].y - bf2f(h.y)); \
      h.z = f2bf(axr[rnd].z); l.z = f2bf(axr[rnd].z - bf2f(h.z)); \
      h.w = f2bf(axr[rnd].w); l.w = f2bf(axr[rnd].w - bf2f(h.w)); \
      *reinterpret_cast<ushort4*>(&Ah[buf][ar[rnd]][ac]) = h; \
      *reinterpret_cast<ushort4*>(&Al[buf][ar[rnd]][ac]) = l; \
    } \
  } while (0)

  // prologue: fully stage buf0
  PQK_BLOAD(0, 0);
  PQK_ALOAD(0);
  PQK_AWRITE(0);
  __syncthreads();

  int cur = 0;
  for (int t = 0; t < 32; ++t) {
    if (t < 31) { PQK_BLOAD(cur ^ 1, (t + 1) * 32); PQK_ALOAD((t + 1) * 32); }

    bf16x8 ah[4], al[4], bh[4], bl[4];
    const int fr = lane & 15, kb = (lane >> 4) * 8;
#pragma unroll
    for (int i = 0; i < 4; ++i) {
      ah[i] = *reinterpret_cast<const bf16x8*>(&Ah[cur][wm + i * 16 + fr][kb]);
      al[i] = *reinterpret_cast<const bf16x8*>(&Al[cur][wm + i * 16 + fr][kb]);
      bh[i] = *reinterpret_cast<const bf16x8*>(&Bh[cur][wn + i * 16 + fr][kb]);
      bl[i] = *reinterpret_cast<const bf16x8*>(&Bl[cur][wn + i * 16 + fr][kb]);
    }
    __builtin_amdgcn_s_setprio(1);
#pragma unroll
    for (int i = 0; i < 4; ++i)
#pragma unroll
      for (int j = 0; j < 4; ++j) {
        acc[i][j] = __builtin_amdgcn_mfma_f32_16x16x32_bf16(ah[i], bh[j], acc[i][j], 0, 0, 0);
        acc[i][j] = __builtin_amdgcn_mfma_f32_16x16x32_bf16(ah[i], bl[j], acc[i][j], 0, 0, 0);
        acc[i][j] = __builtin_amdgcn_mfma_f32_16x16x32_bf16(al[i], bh[j], acc[i][j], 0, 0, 0);
      }
    __builtin_amdgcn_s_setprio(0);

    if (t < 31) PQK_AWRITE(cur ^ 1);
    __syncthreads();
    cur ^= 1;
  }
#undef PQK_BLOAD
#undef PQK_ALOAD
#undef PQK_AWRITE

  const int col = lane & 15, rb = (lane >> 4) * 4;
#pragma unroll
  for (int i = 0; i < 4; ++i)
#pragma unroll
    for (int j = 0; j < 4; ++j) {
      int oc = n0 + wn + j * 16 + col;
      float bv = bias[oc];
#pragma unroll
      for (int q = 0; q < 4; ++q) {
        int row = m0 + wm + i * 16 + rb + q;
        float p = acc[i][j][q] + bv;
        unsigned short h = f2bf(p);
        Ohi[(size_t)row * DD + oc] = h;
        Olo[(size_t)row * DD + oc] = f2bf(p - bf2f(h));
      }
    }
}

// ---------------- v projection: single-term bf16, writes v^T f16; dbuf + T14 ----------------
__global__ __launch_bounds__(256)
void proj_v(const float* __restrict__ X,
            const unsigned short* __restrict__ Wh,
            const float* __restrict__ bias,
            unsigned short* __restrict__ vT)
{
  __shared__ unsigned short As[2][128][40];
  __shared__ unsigned short Bs[2][128][32];
  const int tid = threadIdx.x, lane = tid & 63, wid = tid >> 6;
  const int m0 = blockIdx.x * 128, n0 = blockIdx.y * 128;
  const int wm = (wid >> 1) * 64, wn = (wid & 1) * 64;

  const int ar[4] = { (0*256+tid) >> 3, (1*256+tid) >> 3, (2*256+tid) >> 3, (3*256+tid) >> 3 };
  const int ac = (tid & 7) * 4;
  const int b0r = tid >> 2, b0c = (tid & 3) * 8;
  const int b1r = 64 + (tid >> 2);

  f32x4 acc[4][4] = {};
  float4 axr[4];

#define PV_BLOAD(buf, k0) do { \
    gload16(Wh + (size_t)(n0 + b0r) * DD + (k0) + b0c, &Bs[buf][0][0] + (size_t)tid * 8); \
    gload16(Wh + (size_t)(n0 + b1r) * DD + (k0) + b0c, &Bs[buf][0][0] + (size_t)(256 + tid) * 8); \
  } while (0)
#define PV_ALOAD(k0) do { \
    _Pragma("unroll") \
    for (int rnd = 0; rnd < 4; ++rnd) \
      axr[rnd] = *reinterpret_cast<const float4*>(X + (size_t)(m0 + ar[rnd]) * DD + (k0) + ac); \
  } while (0)
#define PV_AWRITE(buf) do { \
    _Pragma("unroll") \
    for (int rnd = 0; rnd < 4; ++rnd) { \
      ushort4 h; \
      h.x = f2bf(axr[rnd].x); h.y = f2bf(axr[rnd].y); \
      h.z = f2bf(axr[rnd].z); h.w = f2bf(axr[rnd].w); \
      *reinterpret_cast<ushort4*>(&As[buf][ar[rnd]][ac]) = h; \
    } \
  } while (0)

  PV_BLOAD(0, 0);
  PV_ALOAD(0);
  PV_AWRITE(0);
  __syncthreads();

  int cur = 0;
  for (int t = 0; t < 32; ++t) {
    if (t < 31) { PV_BLOAD(cur ^ 1, (t + 1) * 32); PV_ALOAD((t + 1) * 32); }

    bf16x8 a[4], b[4];
    const int fr = lane & 15, kb = (lane >> 4) * 8;
#pragma unroll
    for (int i = 0; i < 4; ++i) {
      a[i] = *reinterpret_cast<const bf16x8*>(&As[cur][wm + i * 16 + fr][kb]);
      b[i] = *reinterpret_cast<const bf16x8*>(&Bs[cur][wn + i * 16 + fr][kb]);
    }
    __builtin_amdgcn_s_setprio(1);
#pragma unroll
    for (int i = 0; i < 4; ++i)
#pragma unroll
      for (int j = 0; j < 4; ++j)
        acc[i][j] = __builtin_amdgcn_mfma_f32_16x16x32_bf16(a[i], b[j], acc[i][j], 0, 0, 0);
    __builtin_amdgcn_s_setprio(0);

    if (t < 31) PV_AWRITE(cur ^ 1);
    __syncthreads();
    cur ^= 1;
  }
#undef PV_BLOAD
#undef PV_ALOAD
#undef PV_AWRITE

  const int col = lane & 15, rb = (lane >> 4) * 4;
#pragma unroll
  for (int i = 0; i < 4; ++i)
#pragma unroll
    for (int j = 0; j < 4; ++j) {
      int oc = n0 + wn + j * 16 + col;
      float bv = bias[oc];
      int row = m0 + wm + i * 16 + rb;
      int bb = row >> 12, s = row & (SS - 1);
      ushort4 h;
      h.x = f2h(acc[i][j][0] + bv);
      h.y = f2h(acc[i][j][1] + bv);
      h.z = f2h(acc[i][j][2] + bv);
      h.w = f2h(acc[i][j][3] + bv);
      *reinterpret_cast<ushort4*>(vT + ((size_t)(bb * DD + oc)) * SS + s) = h;
    }
}

// ---------------- logits v2: 256x256 tile, 8 waves, BK=32, dbuf, swizzled LDS ----------------
__global__ __launch_bounds__(512, 2)
void logits_v2(const unsigned short* __restrict__ qh, const unsigned short* __restrict__ ql,
               const unsigned short* __restrict__ kh, const unsigned short* __restrict__ kl,
               float* __restrict__ out)
{
  __shared__ unsigned short lds[8][8192];   // [dbuf*4 ops][16KB each]
  const int tid = threadIdx.x, lane = tid & 63, wid = tid >> 6;

  int bid = blockIdx.x;
  int swz = (bid & 7) * 128 + (bid >> 3);
  const int b = swz >> 8;
  const int r = swz & 255;
  const int t0 = (r >> 4) * 256, s0 = (r & 15) * 256;

  const unsigned short* qhB = qh + (size_t)b * SS * DD;
  const unsigned short* qlB = ql + (size_t)b * SS * DD;
  const unsigned short* khB = kh + (size_t)b * SS * DD;
  const unsigned short* klB = kl + (size_t)b * SS * DD;

  const int sfr = (tid >> 2) & 15;
  const int scc = (tid & 3) ^ ((sfr >> 1) & 3);
  const int srowl = (tid >> 6) * 16 + sfr;
  const size_t qoff0 = (size_t)(t0 + srowl) * DD + scc * 8;
  const size_t koff0 = (size_t)(s0 + srowl) * DD + scc * 8;
  const int l0s = tid * 8;
  const int l1s = 4096 + tid * 8;

#define STAGE(cur, k0)  do { \
    gload16(qhB + qoff0 + (k0),          &lds[(cur)*4+0][l0s]); \
    gload16(qhB + qoff0 + 131072 + (k0), &lds[(cur)*4+0][l1s]); \
    gload16(qlB + qoff0 + (k0),          &lds[(cur)*4+1][l0s]); \
    gload16(qlB + qoff0 + 131072 + (k0), &lds[(cur)*4+1][l1s]); \
    gload16(khB + koff0 + (k0),          &lds[(cur)*4+2][l0s]); \
    gload16(khB + koff0 + 131072 + (k0), &lds[(cur)*4+2][l1s]); \
    gload16(klB + koff0 + (k0),          &lds[(cur)*4+3][l0s]); \
    gload16(klB + koff0 + 131072 + (k0), &lds[(cur)*4+3][l1s]); \
  } while (0)

  const int wr = wid >> 2, wc = wid & 3;
  const int rfr = lane & 15, rcc = lane >> 4;
  const int lp8 = (rfr * 4 + (rcc ^ ((rfr >> 1) & 3))) * 8;

  f32x4 acc[8][4] = {};

  int cur = 0;
  STAGE(0, 0);
  __syncthreads();

  for (int t = 0; t < 32; ++t) {
    if (t < 31) STAGE(cur ^ 1, (t + 1) * 32);

    bf16x8 bhf[4], blf[4];
#pragma unroll
    for (int n = 0; n < 4; ++n) {
      bhf[n] = *reinterpret_cast<const bf16x8*>(&lds[cur * 4 + 2][(wc * 4 + n) * 512 + lp8]);
      blf[n] = *reinterpret_cast<const bf16x8*>(&lds[cur * 4 + 3][(wc * 4 + n) * 512 + lp8]);
    }
#pragma unroll
    for (int h = 0; h < 2; ++h) {
      bf16x8 ahf[4], alf[4];
#pragma unroll
      for (int m = 0; m < 4; ++m) {
        ahf[m] = *reinterpret_cast<const bf16x8*>(&lds[cur * 4 + 0][(wr * 8 + h * 4 + m) * 512 + lp8]);
        alf[m] = *reinterpret_cast<const bf16x8*>(&lds[cur * 4 + 1][(wr * 8 + h * 4 + m) * 512 + lp8]);
      }
      __builtin_amdgcn_s_setprio(1);
#pragma unroll
      for (int m = 0; m < 4; ++m)
#pragma unroll
        for (int n = 0; n < 4; ++n) {
          acc[h * 4 + m][n] = __builtin_amdgcn_mfma_f32_16x16x32_bf16(ahf[m], bhf[n], acc[h * 4 + m][n], 0, 0, 0);
          acc[h * 4 + m][n] = __builtin_amdgcn_mfma_f32_16x16x32_bf16(ahf[m], blf[n], acc[h * 4 + m][n], 0, 0, 0);
          acc[h * 4 + m][n] = __builtin_amdgcn_mfma_f32_16x16x32_bf16(alf[m], bhf[n], acc[h * 4 + m][n], 0, 0, 0);
        }
      __builtin_amdgcn_s_setprio(0);
    }
    __syncthreads();
    cur ^= 1;
  }
#undef STAGE

  const int col = lane & 15, rb = (lane >> 4) * 4;
#pragma unroll
  for (int m = 0; m < 8; ++m)
#pragma unroll
    for (int n = 0; n < 4; ++n) {
      int s = s0 + wc * 64 + n * 16 + col;
#pragma unroll
      for (int q = 0; q < 4; ++q) {
        int tr = t0 + wr * 128 + m * 16 + rb + q;
        out[((size_t)b * SS + tr) * SS + s] = acc[m][n][q];
      }
    }
}

// ---------------- row softmax in-place ----------------
__global__ __launch_bounds__(256)
void softmax_kernel(float* __restrict__ attn) {
  float* rp = attn + (size_t)blockIdx.x * SS;
  const int tid = threadIdx.x, lane = tid & 63, wid = tid >> 6;
  float v[16];
  float m = -1e30f;
#pragma unroll
  for (int i = 0; i < 4; ++i) {
    float4 x = *reinterpret_cast<const float4*>(rp + i * 1024 + tid * 4);
    v[i * 4 + 0] = x.x; v[i * 4 + 1] = x.y; v[i * 4 + 2] = x.z; v[i * 4 + 3] = x.w;
    m = fmaxf(m, fmaxf(fmaxf(x.x, x.y), fmaxf(x.z, x.w)));
  }
#pragma unroll
  for (int off = 32; off; off >>= 1) m = fmaxf(m, __shfl_xor(m, off));
  __shared__ float redm[4], reds[4];
  if (lane == 0) redm[wid] = m;
  __syncthreads();
  m = fmaxf(fmaxf(redm[0], redm[1]), fmaxf(redm[2], redm[3]));
  float sum = 0.f;
#pragma unroll
  for (int i = 0; i < 16; ++i) { v[i] = __expf(v[i] - m); sum += v[i]; }
#pragma unroll
  for (int off = 32; off; off >>= 1) sum += __shfl_xor(sum, off);
  if (lane == 0) reds[wid] = sum;
  __syncthreads();
  float inv = 1.0f / (reds[0] + reds[1] + reds[2] + reds[3]);
#pragma unroll
  for (int i = 0; i < 4; ++i) {
    float4 x;
    x.x = v[i * 4 + 0] * inv; x.y = v[i * 4 + 1] * inv;
    x.z = v[i * 4 + 2] * inv; x.w = v[i * 4 + 3] * inv;
    *reinterpret_cast<float4*>(rp + i * 1024 + tid * 4) = x;
  }
}

// ---------------- PV GEMM: O = attn * v (f16); dbuf + T14 ----------------
__global__ __launch_bounds__(256)
void pv_f16(const float* __restrict__ attn, const unsigned short* __restrict__ vT,
            float* __restrict__ out)
{
  __shared__ unsigned short As[2][128][40];
  __shared__ unsigned short Bs[2][128][32];
  const int tid = threadIdx.x, lane = tid & 63, wid = tid >> 6;
  const int b = blockIdx.z, t0 = blockIdx.x * 128, n0 = blockIdx.y * 128;
  const float* aB = attn + (size_t)b * SS * SS;
  const unsigned short* vB = vT + ((size_t)b * DD + n0) * SS;
  const int wm = (wid >> 1) * 64, wn = (wid & 1) * 64;

  const int ar[4] = { (0*256+tid) >> 3, (1*256+tid) >> 3, (2*256+tid) >> 3, (3*256+tid) >> 3 };
  const int ac = (tid & 7) * 4;
  const int b0r = tid >> 2, b0c = (tid & 3) * 8;
  const int b1r = 64 + (tid >> 2);

  f32x4 acc[4][4] = {};
  float4 axr[4];

#define PVF_BLOAD(buf, s0) do { \
    gload16(vB + (size_t)b0r * SS + (s0) + b0c, &Bs[buf][0][0] + (size_t)tid * 8); \
    gload16(vB + (size_t)b1r * SS + (s0) + b0c, &Bs[buf][0][0] + (size_t)(256 + tid) * 8); \
  } while (0)
#define PVF_ALOAD(s0) do { \
    _Pragma("unroll") \
    for (int rnd = 0; rnd < 4; ++rnd) \
      axr[rnd] = *reinterpret_cast<const float4*>(aB + (size_t)(t0 + ar[rnd]) * SS + (s0) + ac); \
  } while (0)
#define PVF_AWRITE(buf) do { \
    _Pragma("unroll") \
    for (int rnd = 0; rnd < 4; ++rnd) { \
      ushort4 h; \
      h.x = f2h(axr[rnd].x); h.y = f2h(axr[rnd].y); \
      h.z = f2h(axr[rnd].z); h.w = f2h(axr[rnd].w); \
      *reinterpret_cast<ushort4*>(&As[buf][ar[rnd]][ac]) = h; \
    } \
  } while (0)

  PVF_BLOAD(0, 0);
  PVF_ALOAD(0);
  PVF_AWRITE(0);
  __syncthreads();

  int cur = 0;
  for (int t = 0; t < 128; ++t) {
    if (t < 127) { PVF_BLOAD(cur ^ 1, (t + 1) * 32); PVF_ALOAD((t + 1) * 32); }

    f16x8 a[4], b4[4];
    const int fr = lane & 15, kb = (lane >> 4) * 8;
#pragma unroll
    for (int i = 0; i < 4; ++i) {
      a[i]  = *reinterpret_cast<const f16x8*>(&As[cur][wm + i * 16 + fr][kb]);
      b4[i] = *reinterpret_cast<const f16x8*>(&Bs[cur][wn + i * 16 + fr][kb]);
    }
    __builtin_amdgcn_s_setprio(1);
#pragma unroll
    for (int i = 0; i < 4; ++i)
#pragma unroll
      for (int j = 0; j < 4; ++j)
        acc[i][j] = __builtin_amdgcn_mfma_f32_16x16x32_f16(a[i], b4[j], acc[i][j], 0, 0, 0);
    __builtin_amdgcn_s_setprio(0);

    if (t < 127) PVF_AWRITE(cur ^ 1);
    __syncthreads();
    cur ^= 1;
  }
#undef PVF_BLOAD
#undef PVF_ALOAD
#undef PVF_AWRITE

  const int col = lane & 15, rb = (lane >> 4) * 4;
#pragma unroll
  for (int i = 0; i < 4; ++i)
#pragma unroll
    for (int j = 0; j < 4; ++j) {
      int o = n0 + wn + j * 16 + col;
#pragma unroll
      for (int q = 0; q < 4; ++q) {
        int t = t0 + wm + i * 16 + rb + q;
        out[((size_t)b * SS + t) * DD + o] = acc[i][j][q];
      }
    }
}

extern "C" void kernel_launch(void* const* d_in, const int* in_sizes, int n_in,
                              void* d_out, int out_size, void* d_ws, size_t ws_size,
                              hipStream_t stream) {
  const float* query = (const float*)d_in[0];
  const float* key   = (const float*)d_in[1];
  const float* value = (const float*)d_in[2];
  const float* W     = (const float*)d_in[3];
  const float* bias  = (const float*)d_in[4];

  float* out  = (float*)d_out;                  // [B,S,D]
  float* attn = out + (size_t)BD * SS * DD;     // [B,S,S]

  unsigned short* Whi = (unsigned short*)d_ws;
  unsigned short* Wlo = Whi + (size_t)DD * DD;
  unsigned short* qhi = Wlo + (size_t)DD * DD;
  unsigned short* qlo = qhi + (size_t)RTOT * DD;
  unsigned short* khi = qlo + (size_t)RTOT * DD;
  unsigned short* klo = khi + (size_t)RTOT * DD;
  unsigned short* vT  = klo + (size_t)RTOT * DD;

  split_w_kernel<<<DD * DD / (256 * 4), 256, 0, stream>>>(W, Whi, Wlo);

  proj_qk<<<dim3(RTOT / 128, DD / 128, 2), 256, 0, stream>>>(
      query, key, Whi, Wlo, bias, qhi, qlo, khi, klo);
  proj_v<<<dim3(RTOT / 128, DD / 128), 256, 0, stream>>>(value, Whi, bias, vT);

  logits_v2<<<(SS / 256) * (SS / 256) * BD, 512, 0, stream>>>(qhi, qlo, khi, klo, attn);
  softmax_kernel<<<RTOT, 256, 0, stream>>>(attn);
  pv_f16<<<dim3(SS / 128, DD / 128, BD), 256, 0, stream>>>(attn, vT, out);
}

// Round 6
// 989.510 us; speedup vs baseline: 1.0865x; 1.0865x over previous
//
#include <hip/hip_runtime.h>
#include <hip/hip_bf16.h>
#include <hip/hip_fp16.h>

#define BD 4
#define SS 4096
#define DD 1024
#define RTOT (BD*SS)   // 16384 total rows

typedef _Float16 f16;
typedef __attribute__((ext_vector_type(8))) _Float16 f16x8;
typedef __attribute__((ext_vector_type(8))) short bf16x8;
typedef __attribute__((ext_vector_type(4))) float f32x4;

static __device__ __forceinline__ unsigned short f2bf(float f) {
  unsigned int u = __float_as_uint(f);
  u += 0x7fff + ((u >> 16) & 1);   // RNE
  return (unsigned short)(u >> 16);
}
static __device__ __forceinline__ float bf2f(unsigned short h) {
  return __uint_as_float(((unsigned int)h) << 16);
}
static __device__ __forceinline__ unsigned short f2h(float f) {
  f16 h = (f16)f;
  return __builtin_bit_cast(unsigned short, h);
}
static __device__ __forceinline__ float h2f(unsigned short u) {
  return (float)__builtin_bit_cast(f16, u);
}

// async global->LDS, 16B/lane, wave-uniform LDS base + lane*16
static __device__ __forceinline__ void gload16(const void* g, void* l) {
  __builtin_amdgcn_global_load_lds(
      (const __attribute__((address_space(1))) unsigned int*)g,
      (__attribute__((address_space(3))) unsigned int*)l, 16, 0, 0);
}

// ---------------- split W into hi/lo bf16 ----------------
__global__ void split_w_kernel(const float* __restrict__ W,
                               unsigned short* __restrict__ Whi,
                               unsigned short* __restrict__ Wlo) {
  int i = (blockIdx.x * 256 + threadIdx.x) * 4;
  float4 x = *reinterpret_cast<const float4*>(W + i);
  ushort4 h, l;
  h.x = f2bf(x.x); l.x = f2bf(x.x - bf2f(h.x));
  h.y = f2bf(x.y); l.y = f2bf(x.y - bf2f(h.y));
  h.z = f2bf(x.z); l.z = f2bf(x.z - bf2f(h.z));
  h.w = f2bf(x.w); l.w = f2bf(x.w - bf2f(h.w));
  *reinterpret_cast<ushort4*>(Whi + i) = h;
  *reinterpret_cast<ushort4*>(Wlo + i) = l;
}

// ---------------- q+k projection (fused z): P = X W^T + b, bf16 3-term ----------------
// z=0: write q as single f16.  z=1: write k as f16 hi + f16 lo.
__global__ __launch_bounds__(256)
void proj_qk(const float* __restrict__ Xq, const float* __restrict__ Xk,
             const unsigned short* __restrict__ Wh,
             const unsigned short* __restrict__ Wl,
             const float* __restrict__ bias,
             unsigned short* __restrict__ Oq,
             unsigned short* __restrict__ Okh, unsigned short* __restrict__ Okl)
{
  __shared__ unsigned short Ah[128][40], Al[128][40];   // padded, reg-staged cvt
  __shared__ unsigned short Bh[128][32], Bl[128][32];   // linear, gload_lds
  const int tid = threadIdx.x, lane = tid & 63, wid = tid >> 6;
  const int m0 = blockIdx.x * 128, n0 = blockIdx.y * 128;
  const int wm = (wid >> 1) * 64, wn = (wid & 1) * 64;

  const float* X = blockIdx.z ? Xk : Xq;

  f32x4 acc[4][4] = {};

  for (int k0 = 0; k0 < DD; k0 += 32) {
    __syncthreads();
#pragma unroll
    for (int rnd = 0; rnd < 4; ++rnd) {
      int e = rnd * 256 + tid;
      int r = e >> 3, c = (e & 7) * 4;
      float4 x = *reinterpret_cast<const float4*>(X + (size_t)(m0 + r) * DD + k0 + c);
      ushort4 h, l;
      h.x = f2bf(x.x); l.x = f2bf(x.x - bf2f(h.x));
      h.y = f2bf(x.y); l.y = f2bf(x.y - bf2f(h.y));
      h.z = f2bf(x.z); l.z = f2bf(x.z - bf2f(h.z));
      h.w = f2bf(x.w); l.w = f2bf(x.w - bf2f(h.w));
      *reinterpret_cast<ushort4*>(&Ah[r][c]) = h;
      *reinterpret_cast<ushort4*>(&Al[r][c]) = l;
    }
#pragma unroll
    for (int rnd = 0; rnd < 2; ++rnd) {
      int e = rnd * 256 + tid;
      size_t go = (size_t)(n0 + (e >> 2)) * DD + k0 + (e & 3) * 8;
      gload16(Wh + go, &Bh[0][0] + (size_t)e * 8);
      gload16(Wl + go, &Bl[0][0] + (size_t)e * 8);
    }
    __syncthreads();

    bf16x8 ah[4], al[4], bh[4], bl[4];
    const int fr = lane & 15, kb = (lane >> 4) * 8;
#pragma unroll
    for (int i = 0; i < 4; ++i) {
      ah[i] = *reinterpret_cast<const bf16x8*>(&Ah[wm + i * 16 + fr][kb]);
      al[i] = *reinterpret_cast<const bf16x8*>(&Al[wm + i * 16 + fr][kb]);
      bh[i] = *reinterpret_cast<const bf16x8*>(&Bh[wn + i * 16 + fr][kb]);
      bl[i] = *reinterpret_cast<const bf16x8*>(&Bl[wn + i * 16 + fr][kb]);
    }
#pragma unroll
    for (int i = 0; i < 4; ++i)
#pragma unroll
      for (int j = 0; j < 4; ++j) {
        acc[i][j] = __builtin_amdgcn_mfma_f32_16x16x32_bf16(ah[i], bh[j], acc[i][j], 0, 0, 0);
        acc[i][j] = __builtin_amdgcn_mfma_f32_16x16x32_bf16(ah[i], bl[j], acc[i][j], 0, 0, 0);
        acc[i][j] = __builtin_amdgcn_mfma_f32_16x16x32_bf16(al[i], bh[j], acc[i][j], 0, 0, 0);
      }
  }

  const int col = lane & 15, rb = (lane >> 4) * 4;
#pragma unroll
  for (int i = 0; i < 4; ++i)
#pragma unroll
    for (int j = 0; j < 4; ++j) {
      int oc = n0 + wn + j * 16 + col;
      float bv = bias[oc];
#pragma unroll
      for (int q = 0; q < 4; ++q) {
        int row = m0 + wm + i * 16 + rb + q;
        float p = acc[i][j][q] + bv;
        if (blockIdx.z == 0) {
          Oq[(size_t)row * DD + oc] = f2h(p);
        } else {
          unsigned short h = f2h(p);
          Okh[(size_t)row * DD + oc] = h;
          Okl[(size_t)row * DD + oc] = f2h(p - h2f(h));
        }
      }
    }
}

// ---------------- v projection: single-term bf16, writes v^T f16 [b][o][s] ----------------
__global__ __launch_bounds__(256)
void proj_v(const float* __restrict__ X,
            const unsigned short* __restrict__ Wh,
            const float* __restrict__ bias,
            unsigned short* __restrict__ vT)
{
  __shared__ unsigned short As[128][40];
  __shared__ unsigned short Bs[128][32];
  const int tid = threadIdx.x, lane = tid & 63, wid = tid >> 6;
  const int m0 = blockIdx.x * 128, n0 = blockIdx.y * 128;
  const int wm = (wid >> 1) * 64, wn = (wid & 1) * 64;

  f32x4 acc[4][4] = {};

  for (int k0 = 0; k0 < DD; k0 += 32) {
    __syncthreads();
#pragma unroll
    for (int rnd = 0; rnd < 4; ++rnd) {
      int e = rnd * 256 + tid;
      int r = e >> 3, c = (e & 7) * 4;
      float4 x = *reinterpret_cast<const float4*>(X + (size_t)(m0 + r) * DD + k0 + c);
      ushort4 h;
      h.x = f2bf(x.x); h.y = f2bf(x.y); h.z = f2bf(x.z); h.w = f2bf(x.w);
      *reinterpret_cast<ushort4*>(&As[r][c]) = h;
    }
#pragma unroll
    for (int rnd = 0; rnd < 2; ++rnd) {
      int e = rnd * 256 + tid;
      gload16(Wh + (size_t)(n0 + (e >> 2)) * DD + k0 + (e & 3) * 8,
              &Bs[0][0] + (size_t)e * 8);
    }
    __syncthreads();

    bf16x8 a[4], b[4];
    const int fr = lane & 15, kb = (lane >> 4) * 8;
#pragma unroll
    for (int i = 0; i < 4; ++i) {
      a[i] = *reinterpret_cast<const bf16x8*>(&As[wm + i * 16 + fr][kb]);
      b[i] = *reinterpret_cast<const bf16x8*>(&Bs[wn + i * 16 + fr][kb]);
    }
#pragma unroll
    for (int i = 0; i < 4; ++i)
#pragma unroll
      for (int j = 0; j < 4; ++j)
        acc[i][j] = __builtin_amdgcn_mfma_f32_16x16x32_bf16(a[i], b[j], acc[i][j], 0, 0, 0);
  }

  const int col = lane & 15, rb = (lane >> 4) * 4;
#pragma unroll
  for (int i = 0; i < 4; ++i)
#pragma unroll
    for (int j = 0; j < 4; ++j) {
      int oc = n0 + wn + j * 16 + col;
      float bv = bias[oc];
      int row = m0 + wm + i * 16 + rb;
      int bb = row >> 12, s = row & (SS - 1);
      ushort4 h;
      h.x = f2h(acc[i][j][0] + bv);
      h.y = f2h(acc[i][j][1] + bv);
      h.z = f2h(acc[i][j][2] + bv);
      h.w = f2h(acc[i][j][3] + bv);
      *reinterpret_cast<ushort4*>(vT + ((size_t)(bb * DD + oc)) * SS + s) = h;
    }
}

// ---------------- logits v3: 2-term asymmetric f16 (qf single, k hi/lo) ----------------
// 256x256 tile, 8 waves, BK=32, dbuf, swizzled LDS granules. 96 KiB LDS.
__global__ __launch_bounds__(512, 2)
void logits_v3(const unsigned short* __restrict__ qf,
               const unsigned short* __restrict__ kh, const unsigned short* __restrict__ kl,
               float* __restrict__ out)
{
  __shared__ unsigned short lds[6][8192];   // [dbuf*3 ops][16KB each]
  const int tid = threadIdx.x, lane = tid & 63, wid = tid >> 6;

  int bid = blockIdx.x;
  int swz = (bid & 7) * 128 + (bid >> 3);
  const int b = swz >> 8;
  const int r = swz & 255;
  const int t0 = (r >> 4) * 256, s0 = (r & 15) * 256;

  const unsigned short* qB  = qf + (size_t)b * SS * DD;
  const unsigned short* khB = kh + (size_t)b * SS * DD;
  const unsigned short* klB = kl + (size_t)b * SS * DD;

  const int sfr = (tid >> 2) & 15;
  const int scc = (tid & 3) ^ ((sfr >> 1) & 3);
  const int srowl = (tid >> 6) * 16 + sfr;
  const size_t qoff0 = (size_t)(t0 + srowl) * DD + scc * 8;
  const size_t koff0 = (size_t)(s0 + srowl) * DD + scc * 8;
  const int l0s = tid * 8;
  const int l1s = 4096 + tid * 8;   // +128 rows = 128*DD shorts in global

#define STAGE(cur, k0)  do { \
    gload16(qB  + qoff0 + (k0),          &lds[(cur)*3+0][l0s]); \
    gload16(qB  + qoff0 + 131072 + (k0), &lds[(cur)*3+0][l1s]); \
    gload16(khB + koff0 + (k0),          &lds[(cur)*3+1][l0s]); \
    gload16(khB + koff0 + 131072 + (k0), &lds[(cur)*3+1][l1s]); \
    gload16(klB + koff0 + (k0),          &lds[(cur)*3+2][l0s]); \
    gload16(klB + koff0 + 131072 + (k0), &lds[(cur)*3+2][l1s]); \
  } while (0)

  const int wr = wid >> 2, wc = wid & 3;
  const int rfr = lane & 15, rcc = lane >> 4;
  const int lp8 = (rfr * 4 + (rcc ^ ((rfr >> 1) & 3))) * 8;

  f32x4 acc[8][4] = {};

  int cur = 0;
  STAGE(0, 0);
  __syncthreads();

  for (int t = 0; t < 32; ++t) {
    if (t < 31) STAGE(cur ^ 1, (t + 1) * 32);

    f16x8 bhf[4], blf[4];
#pragma unroll
    for (int n = 0; n < 4; ++n) {
      bhf[n] = *reinterpret_cast<const f16x8*>(&lds[cur * 3 + 1][(wc * 4 + n) * 512 + lp8]);
      blf[n] = *reinterpret_cast<const f16x8*>(&lds[cur * 3 + 2][(wc * 4 + n) * 512 + lp8]);
    }
#pragma unroll
    for (int h = 0; h < 2; ++h) {
      f16x8 ahf[4];
#pragma unroll
      for (int m = 0; m < 4; ++m)
        ahf[m] = *reinterpret_cast<const f16x8*>(&lds[cur * 3 + 0][(wr * 8 + h * 4 + m) * 512 + lp8]);
      __builtin_amdgcn_s_setprio(1);
#pragma unroll
      for (int m = 0; m < 4; ++m)
#pragma unroll
        for (int n = 0; n < 4; ++n) {
          acc[h * 4 + m][n] = __builtin_amdgcn_mfma_f32_16x16x32_f16(ahf[m], bhf[n], acc[h * 4 + m][n], 0, 0, 0);
          acc[h * 4 + m][n] = __builtin_amdgcn_mfma_f32_16x16x32_f16(ahf[m], blf[n], acc[h * 4 + m][n], 0, 0, 0);
        }
      __builtin_amdgcn_s_setprio(0);
    }
    __syncthreads();
    cur ^= 1;
  }
#undef STAGE

  const int col = lane & 15, rb = (lane >> 4) * 4;
#pragma unroll
  for (int m = 0; m < 8; ++m)
#pragma unroll
    for (int n = 0; n < 4; ++n) {
      int s = s0 + wc * 64 + n * 16 + col;
#pragma unroll
      for (int q = 0; q < 4; ++q) {
        int tr = t0 + wr * 128 + m * 16 + rb + q;
        out[((size_t)b * SS + tr) * SS + s] = acc[m][n][q];
      }
    }
}

// ---------------- row softmax in-place ----------------
__global__ __launch_bounds__(256)
void softmax_kernel(float* __restrict__ attn) {
  float* rp = attn + (size_t)blockIdx.x * SS;
  const int tid = threadIdx.x, lane = tid & 63, wid = tid >> 6;
  float v[16];
  float m = -1e30f;
#pragma unroll
  for (int i = 0; i < 4; ++i) {
    float4 x = *reinterpret_cast<const float4*>(rp + i * 1024 + tid * 4);
    v[i * 4 + 0] = x.x; v[i * 4 + 1] = x.y; v[i * 4 + 2] = x.z; v[i * 4 + 3] = x.w;
    m = fmaxf(m, fmaxf(fmaxf(x.x, x.y), fmaxf(x.z, x.w)));
  }
#pragma unroll
  for (int off = 32; off; off >>= 1) m = fmaxf(m, __shfl_xor(m, off));
  __shared__ float redm[4], reds[4];
  if (lane == 0) redm[wid] = m;
  __syncthreads();
  m = fmaxf(fmaxf(redm[0], redm[1]), fmaxf(redm[2], redm[3]));
  float sum = 0.f;
#pragma unroll
  for (int i = 0; i < 16; ++i) { v[i] = __expf(v[i] - m); sum += v[i]; }
#pragma unroll
  for (int off = 32; off; off >>= 1) sum += __shfl_xor(sum, off);
  if (lane == 0) reds[wid] = sum;
  __syncthreads();
  float inv = 1.0f / (reds[0] + reds[1] + reds[2] + reds[3]);
#pragma unroll
  for (int i = 0; i < 4; ++i) {
    float4 x;
    x.x = v[i * 4 + 0] * inv; x.y = v[i * 4 + 1] * inv;
    x.z = v[i * 4 + 2] * inv; x.w = v[i * 4 + 3] * inv;
    *reinterpret_cast<float4*>(rp + i * 1024 + tid * 4) = x;
  }
}

// ---------------- PV GEMM: O[b,t,o] = sum_s attn[t,s] v[s,o] (f16) ----------------
__global__ __launch_bounds__(256)
void pv_f16(const float* __restrict__ attn, const unsigned short* __restrict__ vT,
            float* __restrict__ out)
{
  __shared__ unsigned short As[128][40];
  __shared__ unsigned short Bs[128][32];
  const int tid = threadIdx.x, lane = tid & 63, wid = tid >> 6;
  const int b = blockIdx.z, t0 = blockIdx.x * 128, n0 = blockIdx.y * 128;
  const float* aB = attn + (size_t)b * SS * SS;
  const unsigned short* vB = vT + ((size_t)b * DD + n0) * SS;
  const int wm = (wid >> 1) * 64, wn = (wid & 1) * 64;

  f32x4 acc[4][4] = {};

  for (int s0 = 0; s0 < SS; s0 += 32) {
    __syncthreads();
#pragma unroll
    for (int rnd = 0; rnd < 4; ++rnd) {
      int e = rnd * 256 + tid;
      int r = e >> 3, c = (e & 7) * 4;
      float4 x = *reinterpret_cast<const float4*>(aB + (size_t)(t0 + r) * SS + s0 + c);
      ushort4 h;
      h.x = f2h(x.x); h.y = f2h(x.y); h.z = f2h(x.z); h.w = f2h(x.w);
      *reinterpret_cast<ushort4*>(&As[r][c]) = h;
    }
#pragma unroll
    for (int rnd = 0; rnd < 2; ++rnd) {
      int e = rnd * 256 + tid;
      gload16(vB + (size_t)(e >> 2) * SS + s0 + (e & 3) * 8, &Bs[0][0] + (size_t)e * 8);
    }
    __syncthreads();

    f16x8 a[4], b4[4];
    const int fr = lane & 15, kb = (lane >> 4) * 8;
#pragma unroll
    for (int i = 0; i < 4; ++i) {
      a[i]  = *reinterpret_cast<const f16x8*>(&As[wm + i * 16 + fr][kb]);
      b4[i] = *reinterpret_cast<const f16x8*>(&Bs[wn + i * 16 + fr][kb]);
    }
#pragma unroll
    for (int i = 0; i < 4; ++i)
#pragma unroll
      for (int j = 0; j < 4; ++j)
        acc[i][j] = __builtin_amdgcn_mfma_f32_16x16x32_f16(a[i], b4[j], acc[i][j], 0, 0, 0);
  }

  const int col = lane & 15, rb = (lane >> 4) * 4;
#pragma unroll
  for (int i = 0; i < 4; ++i)
#pragma unroll
    for (int j = 0; j < 4; ++j) {
      int o = n0 + wn + j * 16 + col;
#pragma unroll
      for (int q = 0; q < 4; ++q) {
        int t = t0 + wm + i * 16 + rb + q;
        out[((size_t)b * SS + t) * DD + o] = acc[i][j][q];
      }
    }
}

extern "C" void kernel_launch(void* const* d_in, const int* in_sizes, int n_in,
                              void* d_out, int out_size, void* d_ws, size_t ws_size,
                              hipStream_t stream) {
  const float* query = (const float*)d_in[0];
  const float* key   = (const float*)d_in[1];
  const float* value = (const float*)d_in[2];
  const float* W     = (const float*)d_in[3];
  const float* bias  = (const float*)d_in[4];

  float* out  = (float*)d_out;                  // [B,S,D]
  float* attn = out + (size_t)BD * SS * DD;     // [B,S,S]

  // workspace: Whi/Wlo 4MB + qf/khi/klo/vT 4x33.5MB = ~138 MB
  unsigned short* Whi = (unsigned short*)d_ws;
  unsigned short* Wlo = Whi + (size_t)DD * DD;
  unsigned short* qfb = Wlo + (size_t)DD * DD;
  unsigned short* khi = qfb + (size_t)RTOT * DD;
  unsigned short* klo = khi + (size_t)RTOT * DD;
  unsigned short* vT  = klo + (size_t)RTOT * DD;

  split_w_kernel<<<DD * DD / (256 * 4), 256, 0, stream>>>(W, Whi, Wlo);

  proj_qk<<<dim3(RTOT / 128, DD / 128, 2), 256, 0, stream>>>(
      query, key, Whi, Wlo, bias, qfb, khi, klo);
  proj_v<<<dim3(RTOT / 128, DD / 128), 256, 0, stream>>>(value, Whi, bias, vT);

  logits_v3<<<(SS / 256) * (SS / 256) * BD, 512, 0, stream>>>(qfb, khi, klo, attn);
  softmax_kernel<<<RTOT, 256, 0, stream>>>(attn);
  pv_f16<<<dim3(SS / 128, DD / 128, BD), 256, 0, stream>>>(attn, vT, out);
}

// Round 7
// 934.908 us; speedup vs baseline: 1.1500x; 1.0584x over previous
//
#include <hip/hip_runtime.h>
#include <hip/hip_bf16.h>
#include <hip/hip_fp16.h>

#define BD 4
#define SS 4096
#define DD 1024
#define RTOT (BD*SS)   // 16384 total rows

typedef _Float16 f16;
typedef __attribute__((ext_vector_type(8))) _Float16 f16x8;
typedef __attribute__((ext_vector_type(8))) short bf16x8;
typedef __attribute__((ext_vector_type(4))) float f32x4;

static __device__ __forceinline__ unsigned short f2bf(float f) {
  unsigned int u = __float_as_uint(f);
  u += 0x7fff + ((u >> 16) & 1);   // RNE
  return (unsigned short)(u >> 16);
}
static __device__ __forceinline__ float bf2f(unsigned short h) {
  return __uint_as_float(((unsigned int)h) << 16);
}
static __device__ __forceinline__ unsigned short f2h(float f) {
  f16 h = (f16)f;
  return __builtin_bit_cast(unsigned short, h);
}
static __device__ __forceinline__ float h2f(unsigned short u) {
  return (float)__builtin_bit_cast(f16, u);
}

// async global->LDS, 16B/lane, wave-uniform LDS base + lane*16
static __device__ __forceinline__ void gload16(const void* g, void* l) {
  __builtin_amdgcn_global_load_lds(
      (const __attribute__((address_space(1))) unsigned int*)g,
      (__attribute__((address_space(3))) unsigned int*)l, 16, 0, 0);
}

// ---------------- split W into hi/lo bf16 ----------------
__global__ void split_w_kernel(const float* __restrict__ W,
                               unsigned short* __restrict__ Whi,
                               unsigned short* __restrict__ Wlo) {
  int i = (blockIdx.x * 256 + threadIdx.x) * 4;
  float4 x = *reinterpret_cast<const float4*>(W + i);
  ushort4 h, l;
  h.x = f2bf(x.x); l.x = f2bf(x.x - bf2f(h.x));
  h.y = f2bf(x.y); l.y = f2bf(x.y - bf2f(h.y));
  h.z = f2bf(x.z); l.z = f2bf(x.z - bf2f(h.z));
  h.w = f2bf(x.w); l.w = f2bf(x.w - bf2f(h.w));
  *reinterpret_cast<ushort4*>(Whi + i) = h;
  *reinterpret_cast<ushort4*>(Wlo + i) = l;
}

// ---------------- q+k projection (fused z): P = X W^T + b, bf16 3-term ----------------
// z=0: write q as single f16.  z=1: write k as f16 hi + f16 lo.
__global__ __launch_bounds__(256)
void proj_qk(const float* __restrict__ Xq, const float* __restrict__ Xk,
             const unsigned short* __restrict__ Wh,
             const unsigned short* __restrict__ Wl,
             const float* __restrict__ bias,
             unsigned short* __restrict__ Oq,
             unsigned short* __restrict__ Okh, unsigned short* __restrict__ Okl)
{
  __shared__ unsigned short Ah[128][40], Al[128][40];   // padded, reg-staged cvt
  __shared__ unsigned short Bh[128][32], Bl[128][32];   // linear, gload_lds
  const int tid = threadIdx.x, lane = tid & 63, wid = tid >> 6;
  const int m0 = blockIdx.x * 128, n0 = blockIdx.y * 128;
  const int wm = (wid >> 1) * 64, wn = (wid & 1) * 64;

  const float* X = blockIdx.z ? Xk : Xq;

  f32x4 acc[4][4] = {};

  for (int k0 = 0; k0 < DD; k0 += 32) {
    __syncthreads();
#pragma unroll
    for (int rnd = 0; rnd < 4; ++rnd) {
      int e = rnd * 256 + tid;
      int r = e >> 3, c = (e & 7) * 4;
      float4 x = *reinterpret_cast<const float4*>(X + (size_t)(m0 + r) * DD + k0 + c);
      ushort4 h, l;
      h.x = f2bf(x.x); l.x = f2bf(x.x - bf2f(h.x));
      h.y = f2bf(x.y); l.y = f2bf(x.y - bf2f(h.y));
      h.z = f2bf(x.z); l.z = f2bf(x.z - bf2f(h.z));
      h.w = f2bf(x.w); l.w = f2bf(x.w - bf2f(h.w));
      *reinterpret_cast<ushort4*>(&Ah[r][c]) = h;
      *reinterpret_cast<ushort4*>(&Al[r][c]) = l;
    }
#pragma unroll
    for (int rnd = 0; rnd < 2; ++rnd) {
      int e = rnd * 256 + tid;
      size_t go = (size_t)(n0 + (e >> 2)) * DD + k0 + (e & 3) * 8;
      gload16(Wh + go, &Bh[0][0] + (size_t)e * 8);
      gload16(Wl + go, &Bl[0][0] + (size_t)e * 8);
    }
    __syncthreads();

    bf16x8 ah[4], al[4], bh[4], bl[4];
    const int fr = lane & 15, kb = (lane >> 4) * 8;
#pragma unroll
    for (int i = 0; i < 4; ++i) {
      ah[i] = *reinterpret_cast<const bf16x8*>(&Ah[wm + i * 16 + fr][kb]);
      al[i] = *reinterpret_cast<const bf16x8*>(&Al[wm + i * 16 + fr][kb]);
      bh[i] = *reinterpret_cast<const bf16x8*>(&Bh[wn + i * 16 + fr][kb]);
      bl[i] = *reinterpret_cast<const bf16x8*>(&Bl[wn + i * 16 + fr][kb]);
    }
#pragma unroll
    for (int i = 0; i < 4; ++i)
#pragma unroll
      for (int j = 0; j < 4; ++j) {
        acc[i][j] = __builtin_amdgcn_mfma_f32_16x16x32_bf16(ah[i], bh[j], acc[i][j], 0, 0, 0);
        acc[i][j] = __builtin_amdgcn_mfma_f32_16x16x32_bf16(ah[i], bl[j], acc[i][j], 0, 0, 0);
        acc[i][j] = __builtin_amdgcn_mfma_f32_16x16x32_bf16(al[i], bh[j], acc[i][j], 0, 0, 0);
      }
  }

  const int col = lane & 15, rb = (lane >> 4) * 4;
#pragma unroll
  for (int i = 0; i < 4; ++i)
#pragma unroll
    for (int j = 0; j < 4; ++j) {
      int oc = n0 + wn + j * 16 + col;
      float bv = bias[oc];
#pragma unroll
      for (int q = 0; q < 4; ++q) {
        int row = m0 + wm + i * 16 + rb + q;
        float p = acc[i][j][q] + bv;
        if (blockIdx.z == 0) {
          Oq[(size_t)row * DD + oc] = f2h(p);
        } else {
          unsigned short h = f2h(p);
          Okh[(size_t)row * DD + oc] = h;
          Okl[(size_t)row * DD + oc] = f2h(p - h2f(h));
        }
      }
    }
}

// ---------------- v projection: single-term bf16, writes v^T f16 [b][o][s] ----------------
__global__ __launch_bounds__(256)
void proj_v(const float* __restrict__ X,
            const unsigned short* __restrict__ Wh,
            const float* __restrict__ bias,
            unsigned short* __restrict__ vT)
{
  __shared__ unsigned short As[128][40];
  __shared__ unsigned short Bs[128][32];
  const int tid = threadIdx.x, lane = tid & 63, wid = tid >> 6;
  const int m0 = blockIdx.x * 128, n0 = blockIdx.y * 128;
  const int wm = (wid >> 1) * 64, wn = (wid & 1) * 64;

  f32x4 acc[4][4] = {};

  for (int k0 = 0; k0 < DD; k0 += 32) {
    __syncthreads();
#pragma unroll
    for (int rnd = 0; rnd < 4; ++rnd) {
      int e = rnd * 256 + tid;
      int r = e >> 3, c = (e & 7) * 4;
      float4 x = *reinterpret_cast<const float4*>(X + (size_t)(m0 + r) * DD + k0 + c);
      ushort4 h;
      h.x = f2bf(x.x); h.y = f2bf(x.y); h.z = f2bf(x.z); h.w = f2bf(x.w);
      *reinterpret_cast<ushort4*>(&As[r][c]) = h;
    }
#pragma unroll
    for (int rnd = 0; rnd < 2; ++rnd) {
      int e = rnd * 256 + tid;
      gload16(Wh + (size_t)(n0 + (e >> 2)) * DD + k0 + (e & 3) * 8,
              &Bs[0][0] + (size_t)e * 8);
    }
    __syncthreads();

    bf16x8 a[4], b[4];
    const int fr = lane & 15, kb = (lane >> 4) * 8;
#pragma unroll
    for (int i = 0; i < 4; ++i) {
      a[i] = *reinterpret_cast<const bf16x8*>(&As[wm + i * 16 + fr][kb]);
      b[i] = *reinterpret_cast<const bf16x8*>(&Bs[wn + i * 16 + fr][kb]);
    }
#pragma unroll
    for (int i = 0; i < 4; ++i)
#pragma unroll
      for (int j = 0; j < 4; ++j)
        acc[i][j] = __builtin_amdgcn_mfma_f32_16x16x32_bf16(a[i], b[j], acc[i][j], 0, 0, 0);
  }

  const int col = lane & 15, rb = (lane >> 4) * 4;
#pragma unroll
  for (int i = 0; i < 4; ++i)
#pragma unroll
    for (int j = 0; j < 4; ++j) {
      int oc = n0 + wn + j * 16 + col;
      float bv = bias[oc];
      int row = m0 + wm + i * 16 + rb;
      int bb = row >> 12, s = row & (SS - 1);
      ushort4 h;
      h.x = f2h(acc[i][j][0] + bv);
      h.y = f2h(acc[i][j][1] + bv);
      h.z = f2h(acc[i][j][2] + bv);
      h.w = f2h(acc[i][j][3] + bv);
      *reinterpret_cast<ushort4*>(vT + ((size_t)(bb * DD + oc)) * SS + s) = h;
    }
}

// ---------------- logits v3: 2-term asymmetric f16 (qf single, k hi/lo) ----------------
__global__ __launch_bounds__(512, 2)
void logits_v3(const unsigned short* __restrict__ qf,
               const unsigned short* __restrict__ kh, const unsigned short* __restrict__ kl,
               float* __restrict__ out)
{
  __shared__ unsigned short lds[6][8192];   // [dbuf*3 ops][16KB each]
  const int tid = threadIdx.x, lane = tid & 63, wid = tid >> 6;

  int bid = blockIdx.x;
  int swz = (bid & 7) * 128 + (bid >> 3);
  const int b = swz >> 8;
  const int r = swz & 255;
  const int t0 = (r >> 4) * 256, s0 = (r & 15) * 256;

  const unsigned short* qB  = qf + (size_t)b * SS * DD;
  const unsigned short* khB = kh + (size_t)b * SS * DD;
  const unsigned short* klB = kl + (size_t)b * SS * DD;

  const int sfr = (tid >> 2) & 15;
  const int scc = (tid & 3) ^ ((sfr >> 1) & 3);
  const int srowl = (tid >> 6) * 16 + sfr;
  const size_t qoff0 = (size_t)(t0 + srowl) * DD + scc * 8;
  const size_t koff0 = (size_t)(s0 + srowl) * DD + scc * 8;
  const int l0s = tid * 8;
  const int l1s = 4096 + tid * 8;

#define STAGE(cur, k0)  do { \
    gload16(qB  + qoff0 + (k0),          &lds[(cur)*3+0][l0s]); \
    gload16(qB  + qoff0 + 131072 + (k0), &lds[(cur)*3+0][l1s]); \
    gload16(khB + koff0 + (k0),          &lds[(cur)*3+1][l0s]); \
    gload16(khB + koff0 + 131072 + (k0), &lds[(cur)*3+1][l1s]); \
    gload16(klB + koff0 + (k0),          &lds[(cur)*3+2][l0s]); \
    gload16(klB + koff0 + 131072 + (k0), &lds[(cur)*3+2][l1s]); \
  } while (0)

  const int wr = wid >> 2, wc = wid & 3;
  const int rfr = lane & 15, rcc = lane >> 4;
  const int lp8 = (rfr * 4 + (rcc ^ ((rfr >> 1) & 3))) * 8;

  f32x4 acc[8][4] = {};

  int cur = 0;
  STAGE(0, 0);
  __syncthreads();

  for (int t = 0; t < 32; ++t) {
    if (t < 31) STAGE(cur ^ 1, (t + 1) * 32);

    f16x8 bhf[4], blf[4];
#pragma unroll
    for (int n = 0; n < 4; ++n) {
      bhf[n] = *reinterpret_cast<const f16x8*>(&lds[cur * 3 + 1][(wc * 4 + n) * 512 + lp8]);
      blf[n] = *reinterpret_cast<const f16x8*>(&lds[cur * 3 + 2][(wc * 4 + n) * 512 + lp8]);
    }
#pragma unroll
    for (int h = 0; h < 2; ++h) {
      f16x8 ahf[4];
#pragma unroll
      for (int m = 0; m < 4; ++m)
        ahf[m] = *reinterpret_cast<const f16x8*>(&lds[cur * 3 + 0][(wr * 8 + h * 4 + m) * 512 + lp8]);
      __builtin_amdgcn_s_setprio(1);
#pragma unroll
      for (int m = 0; m < 4; ++m)
#pragma unroll
        for (int n = 0; n < 4; ++n) {
          acc[h * 4 + m][n] = __builtin_amdgcn_mfma_f32_16x16x32_f16(ahf[m], bhf[n], acc[h * 4 + m][n], 0, 0, 0);
          acc[h * 4 + m][n] = __builtin_amdgcn_mfma_f32_16x16x32_f16(ahf[m], blf[n], acc[h * 4 + m][n], 0, 0, 0);
        }
      __builtin_amdgcn_s_setprio(0);
    }
    __syncthreads();
    cur ^= 1;
  }
#undef STAGE

  const int col = lane & 15, rb = (lane >> 4) * 4;
#pragma unroll
  for (int m = 0; m < 8; ++m)
#pragma unroll
    for (int n = 0; n < 4; ++n) {
      int s = s0 + wc * 64 + n * 16 + col;
#pragma unroll
      for (int q = 0; q < 4; ++q) {
        int tr = t0 + wr * 128 + m * 16 + rb + q;
        out[((size_t)b * SS + tr) * SS + s] = acc[m][n][q];
      }
    }
}

// ---------------- row softmax in-place ----------------
__global__ __launch_bounds__(256)
void softmax_kernel(float* __restrict__ attn) {
  float* rp = attn + (size_t)blockIdx.x * SS;
  const int tid = threadIdx.x, lane = tid & 63, wid = tid >> 6;
  float v[16];
  float m = -1e30f;
#pragma unroll
  for (int i = 0; i < 4; ++i) {
    float4 x = *reinterpret_cast<const float4*>(rp + i * 1024 + tid * 4);
    v[i * 4 + 0] = x.x; v[i * 4 + 1] = x.y; v[i * 4 + 2] = x.z; v[i * 4 + 3] = x.w;
    m = fmaxf(m, fmaxf(fmaxf(x.x, x.y), fmaxf(x.z, x.w)));
  }
#pragma unroll
  for (int off = 32; off; off >>= 1) m = fmaxf(m, __shfl_xor(m, off));
  __shared__ float redm[4], reds[4];
  if (lane == 0) redm[wid] = m;
  __syncthreads();
  m = fmaxf(fmaxf(redm[0], redm[1]), fmaxf(redm[2], redm[3]));
  float sum = 0.f;
#pragma unroll
  for (int i = 0; i < 16; ++i) { v[i] = __expf(v[i] - m); sum += v[i]; }
#pragma unroll
  for (int off = 32; off; off >>= 1) sum += __shfl_xor(sum, off);
  if (lane == 0) reds[wid] = sum;
  __syncthreads();
  float inv = 1.0f / (reds[0] + reds[1] + reds[2] + reds[3]);
#pragma unroll
  for (int i = 0; i < 4; ++i) {
    float4 x;
    x.x = v[i * 4 + 0] * inv; x.y = v[i * 4 + 1] * inv;
    x.z = v[i * 4 + 2] * inv; x.w = v[i * 4 + 3] * inv;
    *reinterpret_cast<float4*>(rp + i * 1024 + tid * 4) = x;
  }
}

// ---------------- PV v3: 128(t) x 512(o) tile, 512 thr, 8 waves (2M x 4N) ----------------
// attn re-read factor = DD/512 = 2. B (vT) staged via gload_lds with granule involution.
__global__ __launch_bounds__(512)
void pv_v3(const float* __restrict__ attn, const unsigned short* __restrict__ vT,
           float* __restrict__ out)
{
  __shared__ unsigned short As[128][40];   // padded f16 (reg-staged cvt from fp32)
  __shared__ unsigned short Bs[16384];     // 512x32 f16, granule-swizzled regions
  const int tid = threadIdx.x, lane = tid & 63, wid = tid >> 6;

  int bx = blockIdx.x;
  bx = (bx & 7) * 4 + (bx >> 3);           // XCD swizzle over 32 t-blocks
  const int t0 = bx * 128;
  const int nH = blockIdx.y * 512;
  const int b = blockIdx.z;
  const float* aB = attn + ((size_t)b * SS + t0) * SS;
  const unsigned short* vB = vT + ((size_t)b * DD + nH) * SS;

  const int wr = wid >> 2, wc = wid & 3;   // wave tile 64(t) x 128(o)

  // B stage coords: granule w = tid&63 within region; fr = w>>2, cc = (w&3)^((fr>>1)&3)
  const int sfr = (tid >> 2) & 15;
  const int scc = (tid & 3) ^ ((sfr >> 1) & 3);
  const int brow = (tid >> 6) * 16 + sfr;  // rows 0..127 (round g adds 128g)

  f32x4 acc[4][8] = {};

  for (int s0 = 0; s0 < SS; s0 += 32) {
    __syncthreads();
    // A: 128x32 fp32 -> f16 (2 rounds)
#pragma unroll
    for (int rnd = 0; rnd < 2; ++rnd) {
      int e = rnd * 512 + tid;
      int r = e >> 3, c = (e & 7) * 4;
      float4 x = *reinterpret_cast<const float4*>(aB + (size_t)r * SS + s0 + c);
      ushort4 h;
      h.x = f2h(x.x); h.y = f2h(x.y); h.z = f2h(x.z); h.w = f2h(x.w);
      *reinterpret_cast<ushort4*>(&As[r][c]) = h;
    }
    // B: 512x32 f16, 4 gload rounds, swizzled granule source
#pragma unroll
    for (int g = 0; g < 4; ++g)
      gload16(vB + (size_t)(brow + g * 128) * SS + s0 + scc * 8,
              &Bs[0] + (size_t)g * 4096 + (size_t)tid * 8);
    __syncthreads();

    f16x8 a[4], bb[8];
    const int fr = lane & 15, kb = (lane >> 4) * 8;
    const int lp8 = (fr * 4 + ((lane >> 4) ^ ((fr >> 1) & 3))) * 8;
#pragma unroll
    for (int m = 0; m < 4; ++m)
      a[m] = *reinterpret_cast<const f16x8*>(&As[wr * 64 + m * 16 + fr][kb]);
#pragma unroll
    for (int n = 0; n < 8; ++n)
      bb[n] = *reinterpret_cast<const f16x8*>(&Bs[(wc * 8 + n) * 512 + lp8]);

    __builtin_amdgcn_s_setprio(1);
#pragma unroll
    for (int m = 0; m < 4; ++m)
#pragma unroll
      for (int n = 0; n < 8; ++n)
        acc[m][n] = __builtin_amdgcn_mfma_f32_16x16x32_f16(a[m], bb[n], acc[m][n], 0, 0, 0);
    __builtin_amdgcn_s_setprio(0);
  }

  const int col = lane & 15, rb = (lane >> 4) * 4;
#pragma unroll
  for (int m = 0; m < 4; ++m)
#pragma unroll
    for (int n = 0; n < 8; ++n) {
      int o = nH + wc * 128 + n * 16 + col;
#pragma unroll
      for (int q = 0; q < 4; ++q) {
        int t = t0 + wr * 64 + m * 16 + rb + q;
        out[((size_t)b * SS + t) * DD + o] = acc[m][n][q];
      }
    }
}

extern "C" void kernel_launch(void* const* d_in, const int* in_sizes, int n_in,
                              void* d_out, int out_size, void* d_ws, size_t ws_size,
                              hipStream_t stream) {
  const float* query = (const float*)d_in[0];
  const float* key   = (const float*)d_in[1];
  const float* value = (const float*)d_in[2];
  const float* W     = (const float*)d_in[3];
  const float* bias  = (const float*)d_in[4];

  float* out  = (float*)d_out;                  // [B,S,D]
  float* attn = out + (size_t)BD * SS * DD;     // [B,S,S]

  // workspace: Whi/Wlo 4MB + qf/khi/klo/vT 4x33.5MB = ~138 MB
  unsigned short* Whi = (unsigned short*)d_ws;
  unsigned short* Wlo = Whi + (size_t)DD * DD;
  unsigned short* qfb = Wlo + (size_t)DD * DD;
  unsigned short* khi = qfb + (size_t)RTOT * DD;
  unsigned short* klo = khi + (size_t)RTOT * DD;
  unsigned short* vT  = klo + (size_t)RTOT * DD;

  split_w_kernel<<<DD * DD / (256 * 4), 256, 0, stream>>>(W, Whi, Wlo);

  proj_qk<<<dim3(RTOT / 128, DD / 128, 2), 256, 0, stream>>>(
      query, key, Whi, Wlo, bias, qfb, khi, klo);
  proj_v<<<dim3(RTOT / 128, DD / 128), 256, 0, stream>>>(value, Whi, bias, vT);

  logits_v3<<<(SS / 256) * (SS / 256) * BD, 512, 0, stream>>>(qfb, khi, klo, attn);
  softmax_kernel<<<RTOT, 256, 0, stream>>>(attn);
  pv_v3<<<dim3(SS / 128, DD / 512, BD), 512, 0, stream>>>(attn, vT, out);
}

// Round 8
// 812.015 us; speedup vs baseline: 1.3240x; 1.1513x over previous
//
#include <hip/hip_runtime.h>
#include <hip/hip_bf16.h>
#include <hip/hip_fp16.h>

#define BD 4
#define SS 4096
#define DD 1024
#define RTOT (BD*SS)   // 16384 total rows

typedef _Float16 f16;
typedef __attribute__((ext_vector_type(8))) _Float16 f16x8;
typedef __attribute__((ext_vector_type(4))) float f32x4;

static __device__ __forceinline__ unsigned short f2h(float f) {
  f16 h = (f16)f;
  return __builtin_bit_cast(unsigned short, h);
}
static __device__ __forceinline__ float h2f(unsigned short u) {
  return (float)__builtin_bit_cast(f16, u);
}

// async global->LDS, 16B/lane, wave-uniform LDS base + lane*16
static __device__ __forceinline__ void gload16(const void* g, void* l) {
  __builtin_amdgcn_global_load_lds(
      (const __attribute__((address_space(1))) unsigned int*)g,
      (__attribute__((address_space(3))) unsigned int*)l, 16, 0, 0);
}

// ---------------- X fp32 -> f16 prepass (z selects q/k/v) ----------------
__global__ __launch_bounds__(256)
void convx_kernel(const float* __restrict__ q, const float* __restrict__ k,
                  const float* __restrict__ v,
                  unsigned short* __restrict__ xq, unsigned short* __restrict__ xk,
                  unsigned short* __restrict__ xv) {
  const float* src = blockIdx.z == 0 ? q : (blockIdx.z == 1 ? k : v);
  unsigned short* dst = blockIdx.z == 0 ? xq : (blockIdx.z == 1 ? xk : xv);
  const int n4 = RTOT * DD / 4;
  for (int i = blockIdx.x * 256 + threadIdx.x; i < n4; i += gridDim.x * 256) {
    float4 x = reinterpret_cast<const float4*>(src)[i];
    ushort4 h;
    h.x = f2h(x.x); h.y = f2h(x.y); h.z = f2h(x.z); h.w = f2h(x.w);
    reinterpret_cast<ushort4*>(dst)[i] = h;
  }
}

// ---------------- split W into hi/lo f16 ----------------
__global__ void split_w_kernel(const float* __restrict__ W,
                               unsigned short* __restrict__ Wh,
                               unsigned short* __restrict__ Wl) {
  int i = (blockIdx.x * 256 + threadIdx.x) * 4;
  float4 x = *reinterpret_cast<const float4*>(W + i);
  ushort4 h, l;
  h.x = f2h(x.x); l.x = f2h(x.x - h2f(h.x));
  h.y = f2h(x.y); l.y = f2h(x.y - h2f(h.y));
  h.z = f2h(x.z); l.z = f2h(x.z - h2f(h.z));
  h.w = f2h(x.w); l.w = f2h(x.w - h2f(h.w));
  *reinterpret_cast<ushort4*>(Wh + i) = h;
  *reinterpret_cast<ushort4*>(Wl + i) = l;
}

// ---------------- unified projection: 256x256 tile, 512 thr, logits_v3 clone ----------
// TERMS: 1 (v: Xf*Wh) or 2 (q/k: Xf*Wh + Xf*Wl)
// EPI: 0 = f16 single row-major; 1 = f16 hi/lo row-major; 2 = vT [b][o][s]
template<int TERMS, int EPI>
__global__ __launch_bounds__(512, 2)
void proj_one(const unsigned short* __restrict__ Xf,
              const unsigned short* __restrict__ Wh,
              const unsigned short* __restrict__ Wl,
              const float* __restrict__ bias,
              unsigned short* __restrict__ O1, unsigned short* __restrict__ O2)
{
  constexpr int OPS = 1 + TERMS;
  __shared__ unsigned short lds[2 * OPS][8192];
  const int tid = threadIdx.x, lane = tid & 63, wid = tid >> 6;
  const int t0 = blockIdx.x * 256;   // row tile
  const int n0 = blockIdx.y * 256;   // output-col tile

  const int sfr = (tid >> 2) & 15;
  const int scc = (tid & 3) ^ ((sfr >> 1) & 3);
  const int srowl = (tid >> 6) * 16 + sfr;
  const size_t aoff = (size_t)(t0 + srowl) * DD + scc * 8;
  const size_t boff = (size_t)(n0 + srowl) * DD + scc * 8;
  const int l0s = tid * 8;
  const int l1s = 4096 + tid * 8;   // +128 rows

#define PSTAGE(cur, k0)  do { \
    gload16(Xf + aoff + (k0),          &lds[(cur)*OPS+0][l0s]); \
    gload16(Xf + aoff + 131072 + (k0), &lds[(cur)*OPS+0][l1s]); \
    gload16(Wh + boff + (k0),          &lds[(cur)*OPS+1][l0s]); \
    gload16(Wh + boff + 131072 + (k0), &lds[(cur)*OPS+1][l1s]); \
    if (TERMS == 2) { \
      gload16(Wl + boff + (k0),          &lds[(cur)*OPS+2][l0s]); \
      gload16(Wl + boff + 131072 + (k0), &lds[(cur)*OPS+2][l1s]); \
    } \
  } while (0)

  const int wr = wid >> 2, wc = wid & 3;   // wave tile 128(row) x 64(col)
  const int rfr = lane & 15, rcc = lane >> 4;
  const int lp8 = (rfr * 4 + (rcc ^ ((rfr >> 1) & 3))) * 8;

  f32x4 acc[8][4] = {};

  int cur = 0;
  PSTAGE(0, 0);
  __syncthreads();

  for (int t = 0; t < 32; ++t) {
    if (t < 31) PSTAGE(cur ^ 1, (t + 1) * 32);

    f16x8 bhf[4], blf[4];
#pragma unroll
    for (int n = 0; n < 4; ++n) {
      bhf[n] = *reinterpret_cast<const f16x8*>(&lds[cur * OPS + 1][(wc * 4 + n) * 512 + lp8]);
      if (TERMS == 2)
        blf[n] = *reinterpret_cast<const f16x8*>(&lds[cur * OPS + 2][(wc * 4 + n) * 512 + lp8]);
    }
#pragma unroll
    for (int h = 0; h < 2; ++h) {
      f16x8 ahf[4];
#pragma unroll
      for (int m = 0; m < 4; ++m)
        ahf[m] = *reinterpret_cast<const f16x8*>(&lds[cur * OPS + 0][(wr * 8 + h * 4 + m) * 512 + lp8]);
      __builtin_amdgcn_s_setprio(1);
#pragma unroll
      for (int m = 0; m < 4; ++m)
#pragma unroll
        for (int n = 0; n < 4; ++n) {
          acc[h * 4 + m][n] = __builtin_amdgcn_mfma_f32_16x16x32_f16(ahf[m], bhf[n], acc[h * 4 + m][n], 0, 0, 0);
          if (TERMS == 2)
            acc[h * 4 + m][n] = __builtin_amdgcn_mfma_f32_16x16x32_f16(ahf[m], blf[n], acc[h * 4 + m][n], 0, 0, 0);
        }
      __builtin_amdgcn_s_setprio(0);
    }
    __syncthreads();
    cur ^= 1;
  }
#undef PSTAGE

  const int col = lane & 15, rb = (lane >> 4) * 4;
#pragma unroll
  for (int m = 0; m < 8; ++m)
#pragma unroll
    for (int n = 0; n < 4; ++n) {
      int oc = n0 + wc * 64 + n * 16 + col;
      float bv = bias[oc];
      if (EPI == 2) {
        int tr = t0 + wr * 128 + m * 16 + rb;      // 4 consecutive rows
        int bb = tr >> 12, s = tr & (SS - 1);
        ushort4 h;
        h.x = f2h(acc[m][n][0] + bv);
        h.y = f2h(acc[m][n][1] + bv);
        h.z = f2h(acc[m][n][2] + bv);
        h.w = f2h(acc[m][n][3] + bv);
        *reinterpret_cast<ushort4*>(O1 + ((size_t)(bb * DD + oc)) * SS + s) = h;
      } else {
#pragma unroll
        for (int q = 0; q < 4; ++q) {
          int tr = t0 + wr * 128 + m * 16 + rb + q;
          float p = acc[m][n][q] + bv;
          if (EPI == 0) {
            O1[(size_t)tr * DD + oc] = f2h(p);
          } else {
            unsigned short h = f2h(p);
            O1[(size_t)tr * DD + oc] = h;
            O2[(size_t)tr * DD + oc] = f2h(p - h2f(h));
          }
        }
      }
    }
}

// ---------------- logits v3: 2-term asymmetric f16 (qf single, k hi/lo) ----------------
__global__ __launch_bounds__(512, 2)
void logits_v3(const unsigned short* __restrict__ qf,
               const unsigned short* __restrict__ kh, const unsigned short* __restrict__ kl,
               float* __restrict__ out)
{
  __shared__ unsigned short lds[6][8192];   // [dbuf*3 ops][16KB each]
  const int tid = threadIdx.x, lane = tid & 63, wid = tid >> 6;

  int bid = blockIdx.x;
  int swz = (bid & 7) * 128 + (bid >> 3);
  const int b = swz >> 8;
  const int r = swz & 255;
  const int t0 = (r >> 4) * 256, s0 = (r & 15) * 256;

  const unsigned short* qB  = qf + (size_t)b * SS * DD;
  const unsigned short* khB = kh + (size_t)b * SS * DD;
  const unsigned short* klB = kl + (size_t)b * SS * DD;

  const int sfr = (tid >> 2) & 15;
  const int scc = (tid & 3) ^ ((sfr >> 1) & 3);
  const int srowl = (tid >> 6) * 16 + sfr;
  const size_t qoff0 = (size_t)(t0 + srowl) * DD + scc * 8;
  const size_t koff0 = (size_t)(s0 + srowl) * DD + scc * 8;
  const int l0s = tid * 8;
  const int l1s = 4096 + tid * 8;

#define STAGE(cur, k0)  do { \
    gload16(qB  + qoff0 + (k0),          &lds[(cur)*3+0][l0s]); \
    gload16(qB  + qoff0 + 131072 + (k0), &lds[(cur)*3+0][l1s]); \
    gload16(khB + koff0 + (k0),          &lds[(cur)*3+1][l0s]); \
    gload16(khB + koff0 + 131072 + (k0), &lds[(cur)*3+1][l1s]); \
    gload16(klB + koff0 + (k0),          &lds[(cur)*3+2][l0s]); \
    gload16(klB + koff0 + 131072 + (k0), &lds[(cur)*3+2][l1s]); \
  } while (0)

  const int wr = wid >> 2, wc = wid & 3;
  const int rfr = lane & 15, rcc = lane >> 4;
  const int lp8 = (rfr * 4 + (rcc ^ ((rfr >> 1) & 3))) * 8;

  f32x4 acc[8][4] = {};

  int cur = 0;
  STAGE(0, 0);
  __syncthreads();

  for (int t = 0; t < 32; ++t) {
    if (t < 31) STAGE(cur ^ 1, (t + 1) * 32);

    f16x8 bhf[4], blf[4];
#pragma unroll
    for (int n = 0; n < 4; ++n) {
      bhf[n] = *reinterpret_cast<const f16x8*>(&lds[cur * 3 + 1][(wc * 4 + n) * 512 + lp8]);
      blf[n] = *reinterpret_cast<const f16x8*>(&lds[cur * 3 + 2][(wc * 4 + n) * 512 + lp8]);
    }
#pragma unroll
    for (int h = 0; h < 2; ++h) {
      f16x8 ahf[4];
#pragma unroll
      for (int m = 0; m < 4; ++m)
        ahf[m] = *reinterpret_cast<const f16x8*>(&lds[cur * 3 + 0][(wr * 8 + h * 4 + m) * 512 + lp8]);
      __builtin_amdgcn_s_setprio(1);
#pragma unroll
      for (int m = 0; m < 4; ++m)
#pragma unroll
        for (int n = 0; n < 4; ++n) {
          acc[h * 4 + m][n] = __builtin_amdgcn_mfma_f32_16x16x32_f16(ahf[m], bhf[n], acc[h * 4 + m][n], 0, 0, 0);
          acc[h * 4 + m][n] = __builtin_amdgcn_mfma_f32_16x16x32_f16(ahf[m], blf[n], acc[h * 4 + m][n], 0, 0, 0);
        }
      __builtin_amdgcn_s_setprio(0);
    }
    __syncthreads();
    cur ^= 1;
  }
#undef STAGE

  const int col = lane & 15, rb = (lane >> 4) * 4;
#pragma unroll
  for (int m = 0; m < 8; ++m)
#pragma unroll
    for (int n = 0; n < 4; ++n) {
      int s = s0 + wc * 64 + n * 16 + col;
#pragma unroll
      for (int q = 0; q < 4; ++q) {
        int tr = t0 + wr * 128 + m * 16 + rb + q;
        out[((size_t)b * SS + tr) * SS + s] = acc[m][n][q];
      }
    }
}

// ---------------- row softmax in-place ----------------
__global__ __launch_bounds__(256)
void softmax_kernel(float* __restrict__ attn) {
  float* rp = attn + (size_t)blockIdx.x * SS;
  const int tid = threadIdx.x, lane = tid & 63, wid = tid >> 6;
  float v[16];
  float m = -1e30f;
#pragma unroll
  for (int i = 0; i < 4; ++i) {
    float4 x = *reinterpret_cast<const float4*>(rp + i * 1024 + tid * 4);
    v[i * 4 + 0] = x.x; v[i * 4 + 1] = x.y; v[i * 4 + 2] = x.z; v[i * 4 + 3] = x.w;
    m = fmaxf(m, fmaxf(fmaxf(x.x, x.y), fmaxf(x.z, x.w)));
  }
#pragma unroll
  for (int off = 32; off; off >>= 1) m = fmaxf(m, __shfl_xor(m, off));
  __shared__ float redm[4], reds[4];
  if (lane == 0) redm[wid] = m;
  __syncthreads();
  m = fmaxf(fmaxf(redm[0], redm[1]), fmaxf(redm[2], redm[3]));
  float sum = 0.f;
#pragma unroll
  for (int i = 0; i < 16; ++i) { v[i] = __expf(v[i] - m); sum += v[i]; }
#pragma unroll
  for (int off = 32; off; off >>= 1) sum += __shfl_xor(sum, off);
  if (lane == 0) reds[wid] = sum;
  __syncthreads();
  float inv = 1.0f / (reds[0] + reds[1] + reds[2] + reds[3]);
#pragma unroll
  for (int i = 0; i < 4; ++i) {
    float4 x;
    x.x = v[i * 4 + 0] * inv; x.y = v[i * 4 + 1] * inv;
    x.z = v[i * 4 + 2] * inv; x.w = v[i * 4 + 3] * inv;
    *reinterpret_cast<float4*>(rp + i * 1024 + tid * 4) = x;
  }
}

// ---------------- PV v3: 128(t) x 512(o) tile, 512 thr, 8 waves (2M x 4N) ----------------
__global__ __launch_bounds__(512)
void pv_v3(const float* __restrict__ attn, const unsigned short* __restrict__ vT,
           float* __restrict__ out)
{
  __shared__ unsigned short As[128][40];   // padded f16 (reg-staged cvt from fp32)
  __shared__ unsigned short Bs[16384];     // 512x32 f16, granule-swizzled regions
  const int tid = threadIdx.x, lane = tid & 63, wid = tid >> 6;

  int bx = blockIdx.x;
  bx = (bx & 7) * 4 + (bx >> 3);           // XCD swizzle over 32 t-blocks
  const int t0 = bx * 128;
  const int nH = blockIdx.y * 512;
  const int b = blockIdx.z;
  const float* aB = attn + ((size_t)b * SS + t0) * SS;
  const unsigned short* vB = vT + ((size_t)b * DD + nH) * SS;

  const int wr = wid >> 2, wc = wid & 3;   // wave tile 64(t) x 128(o)

  const int sfr = (tid >> 2) & 15;
  const int scc = (tid & 3) ^ ((sfr >> 1) & 3);
  const int brow = (tid >> 6) * 16 + sfr;  // rows 0..127 (round g adds 128g)

  f32x4 acc[4][8] = {};

  for (int s0 = 0; s0 < SS; s0 += 32) {
    __syncthreads();
#pragma unroll
    for (int rnd = 0; rnd < 2; ++rnd) {
      int e = rnd * 512 + tid;
      int r = e >> 3, c = (e & 7) * 4;
      float4 x = *reinterpret_cast<const float4*>(aB + (size_t)r * SS + s0 + c);
      ushort4 h;
      h.x = f2h(x.x); h.y = f2h(x.y); h.z = f2h(x.z); h.w = f2h(x.w);
      *reinterpret_cast<ushort4*>(&As[r][c]) = h;
    }
#pragma unroll
    for (int g = 0; g < 4; ++g)
      gload16(vB + (size_t)(brow + g * 128) * SS + s0 + scc * 8,
              &Bs[0] + (size_t)g * 4096 + (size_t)tid * 8);
    __syncthreads();

    f16x8 a[4], bb[8];
    const int fr = lane & 15, kb = (lane >> 4) * 8;
    const int lp8 = (fr * 4 + ((lane >> 4) ^ ((fr >> 1) & 3))) * 8;
#pragma unroll
    for (int m = 0; m < 4; ++m)
      a[m] = *reinterpret_cast<const f16x8*>(&As[wr * 64 + m * 16 + fr][kb]);
#pragma unroll
    for (int n = 0; n < 8; ++n)
      bb[n] = *reinterpret_cast<const f16x8*>(&Bs[(wc * 8 + n) * 512 + lp8]);

    __builtin_amdgcn_s_setprio(1);
#pragma unroll
    for (int m = 0; m < 4; ++m)
#pragma unroll
      for (int n = 0; n < 8; ++n)
        acc[m][n] = __builtin_amdgcn_mfma_f32_16x16x32_f16(a[m], bb[n], acc[m][n], 0, 0, 0);
    __builtin_amdgcn_s_setprio(0);
  }

  const int col = lane & 15, rb = (lane >> 4) * 4;
#pragma unroll
  for (int m = 0; m < 4; ++m)
#pragma unroll
    for (int n = 0; n < 8; ++n) {
      int o = nH + wc * 128 + n * 16 + col;
#pragma unroll
      for (int q = 0; q < 4; ++q) {
        int t = t0 + wr * 64 + m * 16 + rb + q;
        out[((size_t)b * SS + t) * DD + o] = acc[m][n][q];
      }
    }
}

extern "C" void kernel_launch(void* const* d_in, const int* in_sizes, int n_in,
                              void* d_out, int out_size, void* d_ws, size_t ws_size,
                              hipStream_t stream) {
  const float* query = (const float*)d_in[0];
  const float* key   = (const float*)d_in[1];
  const float* value = (const float*)d_in[2];
  const float* W     = (const float*)d_in[3];
  const float* bias  = (const float*)d_in[4];

  float* out  = (float*)d_out;                  // [B,S,D]
  float* attn = out + (size_t)BD * SS * DD;     // [B,S,S]

  // workspace (shorts): Whf,Wlf 2x2MB + xq(=vT),xk,xv,qfb,khi,klo 6x33.5MB ~= 205MB
  unsigned short* Whf = (unsigned short*)d_ws;
  unsigned short* Wlf = Whf + (size_t)DD * DD;
  unsigned short* xq  = Wlf + (size_t)DD * DD;   // aliased: vT reuses xq after proj_q
  unsigned short* xk  = xq  + (size_t)RTOT * DD;
  unsigned short* xv  = xk  + (size_t)RTOT * DD;
  unsigned short* qfb = xv  + (size_t)RTOT * DD;
  unsigned short* khi = qfb + (size_t)RTOT * DD;
  unsigned short* klo = khi + (size_t)RTOT * DD;
  unsigned short* vT  = xq;                       // alias (xq dead after proj_q)

  convx_kernel<<<dim3(2048, 1, 3), 256, 0, stream>>>(query, key, value, xq, xk, xv);
  split_w_kernel<<<DD * DD / (256 * 4), 256, 0, stream>>>(W, Whf, Wlf);

  dim3 gp(RTOT / 256, DD / 256);
  proj_one<2, 0><<<gp, 512, 0, stream>>>(xq, Whf, Wlf, bias, qfb, nullptr);
  proj_one<2, 1><<<gp, 512, 0, stream>>>(xk, Whf, Wlf, bias, khi, klo);
  proj_one<1, 2><<<gp, 512, 0, stream>>>(xv, Whf, nullptr, bias, vT, nullptr);

  logits_v3<<<(SS / 256) * (SS / 256) * BD, 512, 0, stream>>>(qfb, khi, klo, attn);
  softmax_kernel<<<RTOT, 256, 0, stream>>>(attn);
  pv_v3<<<dim3(SS / 128, DD / 512, BD), 512, 0, stream>>>(attn, vT, out);
}

// Round 9
// 811.372 us; speedup vs baseline: 1.3251x; 1.0008x over previous
//
#include <hip/hip_runtime.h>
#include <hip/hip_bf16.h>
#include <hip/hip_fp16.h>

#define BD 4
#define SS 4096
#define DD 1024
#define RTOT (BD*SS)   // 16384 total rows

typedef _Float16 f16;
typedef __attribute__((ext_vector_type(8))) _Float16 f16x8;
typedef __attribute__((ext_vector_type(4))) float f32x4;

static __device__ __forceinline__ unsigned short f2h(float f) {
  f16 h = (f16)f;
  return __builtin_bit_cast(unsigned short, h);
}
static __device__ __forceinline__ float h2f(unsigned short u) {
  return (float)__builtin_bit_cast(f16, u);
}

// async global->LDS, 16B/lane, wave-uniform LDS base + lane*16
static __device__ __forceinline__ void gload16(const void* g, void* l) {
  __builtin_amdgcn_global_load_lds(
      (const __attribute__((address_space(1))) unsigned int*)g,
      (__attribute__((address_space(3))) unsigned int*)l, 16, 0, 0);
}

// ---------------- X fp32 -> f16 prepass (z selects q/k/v) ----------------
__global__ __launch_bounds__(256)
void convx_kernel(const float* __restrict__ q, const float* __restrict__ k,
                  const float* __restrict__ v,
                  unsigned short* __restrict__ xq, unsigned short* __restrict__ xk,
                  unsigned short* __restrict__ xv) {
  const float* src = blockIdx.z == 0 ? q : (blockIdx.z == 1 ? k : v);
  unsigned short* dst = blockIdx.z == 0 ? xq : (blockIdx.z == 1 ? xk : xv);
  const int n4 = RTOT * DD / 4;
  for (int i = blockIdx.x * 256 + threadIdx.x; i < n4; i += gridDim.x * 256) {
    float4 x = reinterpret_cast<const float4*>(src)[i];
    ushort4 h;
    h.x = f2h(x.x); h.y = f2h(x.y); h.z = f2h(x.z); h.w = f2h(x.w);
    reinterpret_cast<ushort4*>(dst)[i] = h;
  }
}

// ---------------- split W into hi/lo f16 ----------------
__global__ void split_w_kernel(const float* __restrict__ W,
                               unsigned short* __restrict__ Wh,
                               unsigned short* __restrict__ Wl) {
  int i = (blockIdx.x * 256 + threadIdx.x) * 4;
  float4 x = *reinterpret_cast<const float4*>(W + i);
  ushort4 h, l;
  h.x = f2h(x.x); l.x = f2h(x.x - h2f(h.x));
  h.y = f2h(x.y); l.y = f2h(x.y - h2f(h.y));
  h.z = f2h(x.z); l.z = f2h(x.z - h2f(h.z));
  h.w = f2h(x.w); l.w = f2h(x.w - h2f(h.w));
  *reinterpret_cast<ushort4*>(Wh + i) = h;
  *reinterpret_cast<ushort4*>(Wl + i) = l;
}

// ---------------- unified projection: 256x256 tile, 512 thr ----------
// TERMS: 1 (v: Xf*Wh) or 2 (q/k: Xf*Wh + Xf*Wl)
// EPI: 0 = f16 single row-major; 1 = f16 hi/lo row-major; 2 = vT [b][o][s]
template<int TERMS, int EPI>
__global__ __launch_bounds__(512, 2)
void proj_one(const unsigned short* __restrict__ Xf,
              const unsigned short* __restrict__ Wh,
              const unsigned short* __restrict__ Wl,
              const float* __restrict__ bias,
              unsigned short* __restrict__ O1, unsigned short* __restrict__ O2)
{
  constexpr int OPS = 1 + TERMS;
  __shared__ unsigned short lds[2 * OPS][8192];
  const int tid = threadIdx.x, lane = tid & 63, wid = tid >> 6;
  const int t0 = blockIdx.x * 256;   // row tile
  const int n0 = blockIdx.y * 256;   // output-col tile

  const int sfr = (tid >> 2) & 15;
  const int scc = (tid & 3) ^ ((sfr >> 1) & 3);
  const int srowl = (tid >> 6) * 16 + sfr;
  const size_t aoff = (size_t)(t0 + srowl) * DD + scc * 8;
  const size_t boff = (size_t)(n0 + srowl) * DD + scc * 8;
  const int l0s = tid * 8;
  const int l1s = 4096 + tid * 8;   // +128 rows

#define PSTAGE(cur, k0)  do { \
    gload16(Xf + aoff + (k0),          &lds[(cur)*OPS+0][l0s]); \
    gload16(Xf + aoff + 131072 + (k0), &lds[(cur)*OPS+0][l1s]); \
    gload16(Wh + boff + (k0),          &lds[(cur)*OPS+1][l0s]); \
    gload16(Wh + boff + 131072 + (k0), &lds[(cur)*OPS+1][l1s]); \
    if (TERMS == 2) { \
      gload16(Wl + boff + (k0),          &lds[(cur)*OPS+2][l0s]); \
      gload16(Wl + boff + 131072 + (k0), &lds[(cur)*OPS+2][l1s]); \
    } \
  } while (0)

  const int wr = wid >> 2, wc = wid & 3;   // wave tile 128(row) x 64(col)
  const int rfr = lane & 15, rcc = lane >> 4;
  const int lp8 = (rfr * 4 + (rcc ^ ((rfr >> 1) & 3))) * 8;

  f32x4 acc[8][4] = {};

  int cur = 0;
  PSTAGE(0, 0);
  __syncthreads();

  for (int t = 0; t < 32; ++t) {
    if (t < 31) PSTAGE(cur ^ 1, (t + 1) * 32);

    f16x8 bhf[4], blf[4];
#pragma unroll
    for (int n = 0; n < 4; ++n) {
      bhf[n] = *reinterpret_cast<const f16x8*>(&lds[cur * OPS + 1][(wc * 4 + n) * 512 + lp8]);
      if (TERMS == 2)
        blf[n] = *reinterpret_cast<const f16x8*>(&lds[cur * OPS + 2][(wc * 4 + n) * 512 + lp8]);
    }
#pragma unroll
    for (int h = 0; h < 2; ++h) {
      f16x8 ahf[4];
#pragma unroll
      for (int m = 0; m < 4; ++m)
        ahf[m] = *reinterpret_cast<const f16x8*>(&lds[cur * OPS + 0][(wr * 8 + h * 4 + m) * 512 + lp8]);
      __builtin_amdgcn_s_setprio(1);
#pragma unroll
      for (int m = 0; m < 4; ++m)
#pragma unroll
        for (int n = 0; n < 4; ++n) {
          acc[h * 4 + m][n] = __builtin_amdgcn_mfma_f32_16x16x32_f16(ahf[m], bhf[n], acc[h * 4 + m][n], 0, 0, 0);
          if (TERMS == 2)
            acc[h * 4 + m][n] = __builtin_amdgcn_mfma_f32_16x16x32_f16(ahf[m], blf[n], acc[h * 4 + m][n], 0, 0, 0);
        }
      __builtin_amdgcn_s_setprio(0);
    }
    __syncthreads();
    cur ^= 1;
  }
#undef PSTAGE

  const int col = lane & 15, rb = (lane >> 4) * 4;
#pragma unroll
  for (int m = 0; m < 8; ++m)
#pragma unroll
    for (int n = 0; n < 4; ++n) {
      int oc = n0 + wc * 64 + n * 16 + col;
      float bv = bias[oc];
      if (EPI == 2) {
        int tr = t0 + wr * 128 + m * 16 + rb;      // 4 consecutive rows
        int bb = tr >> 12, s = tr & (SS - 1);
        ushort4 h;
        h.x = f2h(acc[m][n][0] + bv);
        h.y = f2h(acc[m][n][1] + bv);
        h.z = f2h(acc[m][n][2] + bv);
        h.w = f2h(acc[m][n][3] + bv);
        *reinterpret_cast<ushort4*>(O1 + ((size_t)(bb * DD + oc)) * SS + s) = h;
      } else {
#pragma unroll
        for (int q = 0; q < 4; ++q) {
          int tr = t0 + wr * 128 + m * 16 + rb + q;
          float p = acc[m][n][q] + bv;
          if (EPI == 0) {
            O1[(size_t)tr * DD + oc] = f2h(p);
          } else {
            unsigned short h = f2h(p);
            O1[(size_t)tr * DD + oc] = h;
            O2[(size_t)tr * DD + oc] = f2h(p - h2f(h));
          }
        }
      }
    }
}

// ---------------- logits v3: 2-term asymmetric f16 (qf single, k hi/lo) ----------------
__global__ __launch_bounds__(512, 2)
void logits_v3(const unsigned short* __restrict__ qf,
               const unsigned short* __restrict__ kh, const unsigned short* __restrict__ kl,
               float* __restrict__ out)
{
  __shared__ unsigned short lds[6][8192];   // [dbuf*3 ops][16KB each]
  const int tid = threadIdx.x, lane = tid & 63, wid = tid >> 6;

  int bid = blockIdx.x;
  int swz = (bid & 7) * 128 + (bid >> 3);
  const int b = swz >> 8;
  const int r = swz & 255;
  const int t0 = (r >> 4) * 256, s0 = (r & 15) * 256;

  const unsigned short* qB  = qf + (size_t)b * SS * DD;
  const unsigned short* khB = kh + (size_t)b * SS * DD;
  const unsigned short* klB = kl + (size_t)b * SS * DD;

  const int sfr = (tid >> 2) & 15;
  const int scc = (tid & 3) ^ ((sfr >> 1) & 3);
  const int srowl = (tid >> 6) * 16 + sfr;
  const size_t qoff0 = (size_t)(t0 + srowl) * DD + scc * 8;
  const size_t koff0 = (size_t)(s0 + srowl) * DD + scc * 8;
  const int l0s = tid * 8;
  const int l1s = 4096 + tid * 8;

#define STAGE(cur, k0)  do { \
    gload16(qB  + qoff0 + (k0),          &lds[(cur)*3+0][l0s]); \
    gload16(qB  + qoff0 + 131072 + (k0), &lds[(cur)*3+0][l1s]); \
    gload16(khB + koff0 + (k0),          &lds[(cur)*3+1][l0s]); \
    gload16(khB + koff0 + 131072 + (k0), &lds[(cur)*3+1][l1s]); \
    gload16(klB + koff0 + (k0),          &lds[(cur)*3+2][l0s]); \
    gload16(klB + koff0 + 131072 + (k0), &lds[(cur)*3+2][l1s]); \
  } while (0)

  const int wr = wid >> 2, wc = wid & 3;
  const int rfr = lane & 15, rcc = lane >> 4;
  const int lp8 = (rfr * 4 + (rcc ^ ((rfr >> 1) & 3))) * 8;

  f32x4 acc[8][4] = {};

  int cur = 0;
  STAGE(0, 0);
  __syncthreads();

  for (int t = 0; t < 32; ++t) {
    if (t < 31) STAGE(cur ^ 1, (t + 1) * 32);

    f16x8 bhf[4], blf[4];
#pragma unroll
    for (int n = 0; n < 4; ++n) {
      bhf[n] = *reinterpret_cast<const f16x8*>(&lds[cur * 3 + 1][(wc * 4 + n) * 512 + lp8]);
      blf[n] = *reinterpret_cast<const f16x8*>(&lds[cur * 3 + 2][(wc * 4 + n) * 512 + lp8]);
    }
#pragma unroll
    for (int h = 0; h < 2; ++h) {
      f16x8 ahf[4];
#pragma unroll
      for (int m = 0; m < 4; ++m)
        ahf[m] = *reinterpret_cast<const f16x8*>(&lds[cur * 3 + 0][(wr * 8 + h * 4 + m) * 512 + lp8]);
      __builtin_amdgcn_s_setprio(1);
#pragma unroll
      for (int m = 0; m < 4; ++m)
#pragma unroll
        for (int n = 0; n < 4; ++n) {
          acc[h * 4 + m][n] = __builtin_amdgcn_mfma_f32_16x16x32_f16(ahf[m], bhf[n], acc[h * 4 + m][n], 0, 0, 0);
          acc[h * 4 + m][n] = __builtin_amdgcn_mfma_f32_16x16x32_f16(ahf[m], blf[n], acc[h * 4 + m][n], 0, 0, 0);
        }
      __builtin_amdgcn_s_setprio(0);
    }
    __syncthreads();
    cur ^= 1;
  }
#undef STAGE

  const int col = lane & 15, rb = (lane >> 4) * 4;
#pragma unroll
  for (int m = 0; m < 8; ++m)
#pragma unroll
    for (int n = 0; n < 4; ++n) {
      int s = s0 + wc * 64 + n * 16 + col;
#pragma unroll
      for (int q = 0; q < 4; ++q) {
        int tr = t0 + wr * 128 + m * 16 + rb + q;
        out[((size_t)b * SS + tr) * SS + s] = acc[m][n][q];
      }
    }
}

// ---------------- row softmax in-place ----------------
__global__ __launch_bounds__(256)
void softmax_kernel(float* __restrict__ attn) {
  float* rp = attn + (size_t)blockIdx.x * SS;
  const int tid = threadIdx.x, lane = tid & 63, wid = tid >> 6;
  float v[16];
  float m = -1e30f;
#pragma unroll
  for (int i = 0; i < 4; ++i) {
    float4 x = *reinterpret_cast<const float4*>(rp + i * 1024 + tid * 4);
    v[i * 4 + 0] = x.x; v[i * 4 + 1] = x.y; v[i * 4 + 2] = x.z; v[i * 4 + 3] = x.w;
    m = fmaxf(m, fmaxf(fmaxf(x.x, x.y), fmaxf(x.z, x.w)));
  }
#pragma unroll
  for (int off = 32; off; off >>= 1) m = fmaxf(m, __shfl_xor(m, off));
  __shared__ float redm[4], reds[4];
  if (lane == 0) redm[wid] = m;
  __syncthreads();
  m = fmaxf(fmaxf(redm[0], redm[1]), fmaxf(redm[2], redm[3]));
  float sum = 0.f;
#pragma unroll
  for (int i = 0; i < 16; ++i) { v[i] = __expf(v[i] - m); sum += v[i]; }
#pragma unroll
  for (int off = 32; off; off >>= 1) sum += __shfl_xor(sum, off);
  if (lane == 0) reds[wid] = sum;
  __syncthreads();
  float inv = 1.0f / (reds[0] + reds[1] + reds[2] + reds[3]);
#pragma unroll
  for (int i = 0; i < 4; ++i) {
    float4 x;
    x.x = v[i * 4 + 0] * inv; x.y = v[i * 4 + 1] * inv;
    x.z = v[i * 4 + 2] * inv; x.w = v[i * 4 + 3] * inv;
    *reinterpret_cast<float4*>(rp + i * 1024 + tid * 4) = x;
  }
}

// ---------------- PV v4: 64(t) x 512(o) tile, 512 thr, 8 waves (1M x 8N), dbuf prefetch ----
__global__ __launch_bounds__(512, 2)
void pv_v4(const float* __restrict__ attn, const unsigned short* __restrict__ vT,
           float* __restrict__ out)
{
  __shared__ unsigned short As[2][64][40];  // padded f16 (reg-staged cvt from fp32), 10 KB
  __shared__ unsigned short Bs[2][16384];   // 512x32 f16 granule-swizzled, 64 KB
  const int tid = threadIdx.x, lane = tid & 63, wid = tid >> 6;

  int bid = blockIdx.x;
  int bx = (bid & 7) * 8 + (bid >> 3);      // XCD swizzle over 64 t-blocks
  const int t0 = bx * 64;
  const int nH = blockIdx.y * 512;
  const int b = blockIdx.z;
  const float* aB = attn + ((size_t)b * SS + t0) * SS;
  const unsigned short* vB = vT + ((size_t)b * DD + nH) * SS;

  // A stage coords: 64x32 fp32, 1 float4 per thread
  const int arow = tid >> 3, acol = (tid & 7) * 4;
  // B stage coords (granule involution)
  const int sfr = (tid >> 2) & 15;
  const int scc = (tid & 3) ^ ((sfr >> 1) & 3);
  const int brow = (tid >> 6) * 16 + sfr;

  f32x4 acc[4][4] = {};
  float4 areg;

#define PVB_LOAD(buf, s0) do { \
    _Pragma("unroll") \
    for (int g = 0; g < 4; ++g) \
      gload16(vB + (size_t)(brow + g * 128) * SS + (s0) + scc * 8, \
              &Bs[buf][0] + (size_t)g * 4096 + (size_t)tid * 8); \
  } while (0)
#define PVA_WRITE(buf) do { \
    ushort4 h; \
    h.x = f2h(areg.x); h.y = f2h(areg.y); h.z = f2h(areg.z); h.w = f2h(areg.w); \
    *reinterpret_cast<ushort4*>(&As[buf][arow][acol]) = h; \
  } while (0)

  // prologue
  PVB_LOAD(0, 0);
  areg = *reinterpret_cast<const float4*>(aB + (size_t)arow * SS + acol);
  PVA_WRITE(0);
  __syncthreads();

  int cur = 0;
  for (int it = 0; it < 128; ++it) {
    if (it < 127) {
      PVB_LOAD(cur ^ 1, (it + 1) * 32);
      areg = *reinterpret_cast<const float4*>(aB + (size_t)arow * SS + (it + 1) * 32 + acol);
    }

    f16x8 a[4], bb[4];
    const int fr = lane & 15, kb = (lane >> 4) * 8;
    const int lp8 = (fr * 4 + ((lane >> 4) ^ ((fr >> 1) & 3))) * 8;
#pragma unroll
    for (int m = 0; m < 4; ++m)
      a[m] = *reinterpret_cast<const f16x8*>(&As[cur][m * 16 + fr][kb]);
#pragma unroll
    for (int n = 0; n < 4; ++n)
      bb[n] = *reinterpret_cast<const f16x8*>(&Bs[cur][(wid * 4 + n) * 512 + lp8]);

    __builtin_amdgcn_s_setprio(1);
#pragma unroll
    for (int m = 0; m < 4; ++m)
#pragma unroll
      for (int n = 0; n < 4; ++n)
        acc[m][n] = __builtin_amdgcn_mfma_f32_16x16x32_f16(a[m], bb[n], acc[m][n], 0, 0, 0);
    __builtin_amdgcn_s_setprio(0);

    if (it < 127) PVA_WRITE(cur ^ 1);
    __syncthreads();
    cur ^= 1;
  }
#undef PVB_LOAD
#undef PVA_WRITE

  const int col = lane & 15, rb = (lane >> 4) * 4;
#pragma unroll
  for (int m = 0; m < 4; ++m)
#pragma unroll
    for (int n = 0; n < 4; ++n) {
      int o = nH + wid * 64 + n * 16 + col;
#pragma unroll
      for (int q = 0; q < 4; ++q) {
        int t = t0 + m * 16 + rb + q;
        out[((size_t)b * SS + t) * DD + o] = acc[m][n][q];
      }
    }
}

extern "C" void kernel_launch(void* const* d_in, const int* in_sizes, int n_in,
                              void* d_out, int out_size, void* d_ws, size_t ws_size,
                              hipStream_t stream) {
  const float* query = (const float*)d_in[0];
  const float* key   = (const float*)d_in[1];
  const float* value = (const float*)d_in[2];
  const float* W     = (const float*)d_in[3];
  const float* bias  = (const float*)d_in[4];

  float* out  = (float*)d_out;                  // [B,S,D]
  float* attn = out + (size_t)BD * SS * DD;     // [B,S,S]

  // workspace (shorts): Whf,Wlf 2x2MB + xq(=vT),xk,xv,qfb,khi,klo 6x33.5MB ~= 205MB
  unsigned short* Whf = (unsigned short*)d_ws;
  unsigned short* Wlf = Whf + (size_t)DD * DD;
  unsigned short* xq  = Wlf + (size_t)DD * DD;   // aliased: vT reuses xq after proj_q
  unsigned short* xk  = xq  + (size_t)RTOT * DD;
  unsigned short* xv  = xk  + (size_t)RTOT * DD;
  unsigned short* qfb = xv  + (size_t)RTOT * DD;
  unsigned short* khi = qfb + (size_t)RTOT * DD;
  unsigned short* klo = khi + (size_t)RTOT * DD;
  unsigned short* vT  = xq;                       // alias (xq dead after proj_q)

  convx_kernel<<<dim3(2048, 1, 3), 256, 0, stream>>>(query, key, value, xq, xk, xv);
  split_w_kernel<<<DD * DD / (256 * 4), 256, 0, stream>>>(W, Whf, Wlf);

  dim3 gp(RTOT / 256, DD / 256);
  proj_one<2, 0><<<gp, 512, 0, stream>>>(xq, Whf, Wlf, bias, qfb, nullptr);
  proj_one<2, 1><<<gp, 512, 0, stream>>>(xk, Whf, Wlf, bias, khi, klo);
  proj_one<1, 2><<<gp, 512, 0, stream>>>(xv, Whf, nullptr, bias, vT, nullptr);

  logits_v3<<<(SS / 256) * (SS / 256) * BD, 512, 0, stream>>>(qfb, khi, klo, attn);
  softmax_kernel<<<RTOT, 256, 0, stream>>>(attn);
  pv_v4<<<dim3(SS / 64, DD / 512, BD), 512, 0, stream>>>(attn, vT, out);
}

// Round 10
// 734.420 us; speedup vs baseline: 1.4639x; 1.1048x over previous
//
#include <hip/hip_runtime.h>
#include <hip/hip_bf16.h>
#include <hip/hip_fp16.h>

#define BD 4
#define SS 4096
#define DD 1024
#define RTOT (BD*SS)   // 16384 total rows

typedef _Float16 f16;
typedef __attribute__((ext_vector_type(8))) _Float16 f16x8;
typedef __attribute__((ext_vector_type(4))) float f32x4;

static __device__ __forceinline__ unsigned short f2h(float f) {
  f16 h = (f16)f;
  return __builtin_bit_cast(unsigned short, h);
}
static __device__ __forceinline__ float h2f(unsigned short u) {
  return (float)__builtin_bit_cast(f16, u);
}

// async global->LDS, 16B/lane, wave-uniform LDS base + lane*16
static __device__ __forceinline__ void gload16(const void* g, void* l) {
  __builtin_amdgcn_global_load_lds(
      (const __attribute__((address_space(1))) unsigned int*)g,
      (__attribute__((address_space(3))) unsigned int*)l, 16, 0, 0);
}

// ---------------- X fp32 -> f16 prepass (z selects q/k/v) ----------------
__global__ __launch_bounds__(256)
void convx_kernel(const float* __restrict__ q, const float* __restrict__ k,
                  const float* __restrict__ v,
                  unsigned short* __restrict__ xq, unsigned short* __restrict__ xk,
                  unsigned short* __restrict__ xv) {
  const float* src = blockIdx.z == 0 ? q : (blockIdx.z == 1 ? k : v);
  unsigned short* dst = blockIdx.z == 0 ? xq : (blockIdx.z == 1 ? xk : xv);
  const int n4 = RTOT * DD / 4;
  for (int i = blockIdx.x * 256 + threadIdx.x; i < n4; i += gridDim.x * 256) {
    float4 x = reinterpret_cast<const float4*>(src)[i];
    ushort4 h;
    h.x = f2h(x.x); h.y = f2h(x.y); h.z = f2h(x.z); h.w = f2h(x.w);
    reinterpret_cast<ushort4*>(dst)[i] = h;
  }
}

// ---------------- split W into hi/lo f16 ----------------
__global__ void split_w_kernel(const float* __restrict__ W,
                               unsigned short* __restrict__ Wh,
                               unsigned short* __restrict__ Wl) {
  int i = (blockIdx.x * 256 + threadIdx.x) * 4;
  float4 x = *reinterpret_cast<const float4*>(W + i);
  ushort4 h, l;
  h.x = f2h(x.x); l.x = f2h(x.x - h2f(h.x));
  h.y = f2h(x.y); l.y = f2h(x.y - h2f(h.y));
  h.z = f2h(x.z); l.z = f2h(x.z - h2f(h.z));
  h.w = f2h(x.w); l.w = f2h(x.w - h2f(h.w));
  *reinterpret_cast<ushort4*>(Wh + i) = h;
  *reinterpret_cast<ushort4*>(Wl + i) = l;
}

// ---------------- unified projection: 256x256 tile, 512 thr ----------
// TERMS: 1 (v: Xf*Wh) or 2 (q/k: Xf*Wh + Xf*Wl)
// EPI: 0 = f16 single row-major; 1 = f16 hi/lo row-major; 2 = vT [b][o][s]
template<int TERMS, int EPI>
__global__ __launch_bounds__(512, 2)
void proj_one(const unsigned short* __restrict__ Xf,
              const unsigned short* __restrict__ Wh,
              const unsigned short* __restrict__ Wl,
              const float* __restrict__ bias,
              unsigned short* __restrict__ O1, unsigned short* __restrict__ O2)
{
  constexpr int OPS = 1 + TERMS;
  __shared__ unsigned short lds[2 * OPS][8192];
  const int tid = threadIdx.x, lane = tid & 63, wid = tid >> 6;
  const int t0 = blockIdx.x * 256;   // row tile
  const int n0 = blockIdx.y * 256;   // output-col tile

  const int sfr = (tid >> 2) & 15;
  const int scc = (tid & 3) ^ ((sfr >> 1) & 3);
  const int srowl = (tid >> 6) * 16 + sfr;
  const size_t aoff = (size_t)(t0 + srowl) * DD + scc * 8;
  const size_t boff = (size_t)(n0 + srowl) * DD + scc * 8;
  const int l0s = tid * 8;
  const int l1s = 4096 + tid * 8;   // +128 rows

#define PSTAGE(cur, k0)  do { \
    gload16(Xf + aoff + (k0),          &lds[(cur)*OPS+0][l0s]); \
    gload16(Xf + aoff + 131072 + (k0), &lds[(cur)*OPS+0][l1s]); \
    gload16(Wh + boff + (k0),          &lds[(cur)*OPS+1][l0s]); \
    gload16(Wh + boff + 131072 + (k0), &lds[(cur)*OPS+1][l1s]); \
    if (TERMS == 2) { \
      gload16(Wl + boff + (k0),          &lds[(cur)*OPS+2][l0s]); \
      gload16(Wl + boff + 131072 + (k0), &lds[(cur)*OPS+2][l1s]); \
    } \
  } while (0)

  const int wr = wid >> 2, wc = wid & 3;   // wave tile 128(row) x 64(col)
  const int rfr = lane & 15, rcc = lane >> 4;
  const int lp8 = (rfr * 4 + (rcc ^ ((rfr >> 1) & 3))) * 8;

  f32x4 acc[8][4] = {};

  int cur = 0;
  PSTAGE(0, 0);
  __syncthreads();

  for (int t = 0; t < 32; ++t) {
    if (t < 31) PSTAGE(cur ^ 1, (t + 1) * 32);

    f16x8 bhf[4], blf[4];
#pragma unroll
    for (int n = 0; n < 4; ++n) {
      bhf[n] = *reinterpret_cast<const f16x8*>(&lds[cur * OPS + 1][(wc * 4 + n) * 512 + lp8]);
      if (TERMS == 2)
        blf[n] = *reinterpret_cast<const f16x8*>(&lds[cur * OPS + 2][(wc * 4 + n) * 512 + lp8]);
    }
#pragma unroll
    for (int h = 0; h < 2; ++h) {
      f16x8 ahf[4];
#pragma unroll
      for (int m = 0; m < 4; ++m)
        ahf[m] = *reinterpret_cast<const f16x8*>(&lds[cur * OPS + 0][(wr * 8 + h * 4 + m) * 512 + lp8]);
      __builtin_amdgcn_s_setprio(1);
#pragma unroll
      for (int m = 0; m < 4; ++m)
#pragma unroll
        for (int n = 0; n < 4; ++n) {
          acc[h * 4 + m][n] = __builtin_amdgcn_mfma_f32_16x16x32_f16(ahf[m], bhf[n], acc[h * 4 + m][n], 0, 0, 0);
          if (TERMS == 2)
            acc[h * 4 + m][n] = __builtin_amdgcn_mfma_f32_16x16x32_f16(ahf[m], blf[n], acc[h * 4 + m][n], 0, 0, 0);
        }
      __builtin_amdgcn_s_setprio(0);
    }
    __syncthreads();
    cur ^= 1;
  }
#undef PSTAGE

  const int col = lane & 15, rb = (lane >> 4) * 4;
#pragma unroll
  for (int m = 0; m < 8; ++m)
#pragma unroll
    for (int n = 0; n < 4; ++n) {
      int oc = n0 + wc * 64 + n * 16 + col;
      float bv = bias[oc];
      if (EPI == 2) {
        int tr = t0 + wr * 128 + m * 16 + rb;      // 4 consecutive rows
        int bb = tr >> 12, s = tr & (SS - 1);
        ushort4 h;
        h.x = f2h(acc[m][n][0] + bv);
        h.y = f2h(acc[m][n][1] + bv);
        h.z = f2h(acc[m][n][2] + bv);
        h.w = f2h(acc[m][n][3] + bv);
        *reinterpret_cast<ushort4*>(O1 + ((size_t)(bb * DD + oc)) * SS + s) = h;
      } else {
#pragma unroll
        for (int q = 0; q < 4; ++q) {
          int tr = t0 + wr * 128 + m * 16 + rb + q;
          float p = acc[m][n][q] + bv;
          if (EPI == 0) {
            O1[(size_t)tr * DD + oc] = f2h(p);
          } else {
            unsigned short h = f2h(p);
            O1[(size_t)tr * DD + oc] = h;
            O2[(size_t)tr * DD + oc] = f2h(p - h2f(h));
          }
        }
      }
    }
}

// ---------------- logits v3: 2-term asymmetric f16 (qf single, k hi/lo) ----------------
__global__ __launch_bounds__(512, 2)
void logits_v3(const unsigned short* __restrict__ qf,
               const unsigned short* __restrict__ kh, const unsigned short* __restrict__ kl,
               float* __restrict__ out)
{
  __shared__ unsigned short lds[6][8192];   // [dbuf*3 ops][16KB each]
  const int tid = threadIdx.x, lane = tid & 63, wid = tid >> 6;

  int bid = blockIdx.x;
  int swz = (bid & 7) * 128 + (bid >> 3);
  const int b = swz >> 8;
  const int r = swz & 255;
  const int t0 = (r >> 4) * 256, s0 = (r & 15) * 256;

  const unsigned short* qB  = qf + (size_t)b * SS * DD;
  const unsigned short* khB = kh + (size_t)b * SS * DD;
  const unsigned short* klB = kl + (size_t)b * SS * DD;

  const int sfr = (tid >> 2) & 15;
  const int scc = (tid & 3) ^ ((sfr >> 1) & 3);
  const int srowl = (tid >> 6) * 16 + sfr;
  const size_t qoff0 = (size_t)(t0 + srowl) * DD + scc * 8;
  const size_t koff0 = (size_t)(s0 + srowl) * DD + scc * 8;
  const int l0s = tid * 8;
  const int l1s = 4096 + tid * 8;

#define STAGE(cur, k0)  do { \
    gload16(qB  + qoff0 + (k0),          &lds[(cur)*3+0][l0s]); \
    gload16(qB  + qoff0 + 131072 + (k0), &lds[(cur)*3+0][l1s]); \
    gload16(khB + koff0 + (k0),          &lds[(cur)*3+1][l0s]); \
    gload16(khB + koff0 + 131072 + (k0), &lds[(cur)*3+1][l1s]); \
    gload16(klB + koff0 + (k0),          &lds[(cur)*3+2][l0s]); \
    gload16(klB + koff0 + 131072 + (k0), &lds[(cur)*3+2][l1s]); \
  } while (0)

  const int wr = wid >> 2, wc = wid & 3;
  const int rfr = lane & 15, rcc = lane >> 4;
  const int lp8 = (rfr * 4 + (rcc ^ ((rfr >> 1) & 3))) * 8;

  f32x4 acc[8][4] = {};

  int cur = 0;
  STAGE(0, 0);
  __syncthreads();

  for (int t = 0; t < 32; ++t) {
    if (t < 31) STAGE(cur ^ 1, (t + 1) * 32);

    f16x8 bhf[4], blf[4];
#pragma unroll
    for (int n = 0; n < 4; ++n) {
      bhf[n] = *reinterpret_cast<const f16x8*>(&lds[cur * 3 + 1][(wc * 4 + n) * 512 + lp8]);
      blf[n] = *reinterpret_cast<const f16x8*>(&lds[cur * 3 + 2][(wc * 4 + n) * 512 + lp8]);
    }
#pragma unroll
    for (int h = 0; h < 2; ++h) {
      f16x8 ahf[4];
#pragma unroll
      for (int m = 0; m < 4; ++m)
        ahf[m] = *reinterpret_cast<const f16x8*>(&lds[cur * 3 + 0][(wr * 8 + h * 4 + m) * 512 + lp8]);
      __builtin_amdgcn_s_setprio(1);
#pragma unroll
      for (int m = 0; m < 4; ++m)
#pragma unroll
        for (int n = 0; n < 4; ++n) {
          acc[h * 4 + m][n] = __builtin_amdgcn_mfma_f32_16x16x32_f16(ahf[m], bhf[n], acc[h * 4 + m][n], 0, 0, 0);
          acc[h * 4 + m][n] = __builtin_amdgcn_mfma_f32_16x16x32_f16(ahf[m], blf[n], acc[h * 4 + m][n], 0, 0, 0);
        }
      __builtin_amdgcn_s_setprio(0);
    }
    __syncthreads();
    cur ^= 1;
  }
#undef STAGE

  const int col = lane & 15, rb = (lane >> 4) * 4;
#pragma unroll
  for (int m = 0; m < 8; ++m)
#pragma unroll
    for (int n = 0; n < 4; ++n) {
      int s = s0 + wc * 64 + n * 16 + col;
#pragma unroll
      for (int q = 0; q < 4; ++q) {
        int tr = t0 + wr * 128 + m * 16 + rb + q;
        out[((size_t)b * SS + tr) * SS + s] = acc[m][n][q];
      }
    }
}

// ---------------- row softmax in-place ----------------
__global__ __launch_bounds__(256)
void softmax_kernel(float* __restrict__ attn) {
  float* rp = attn + (size_t)blockIdx.x * SS;
  const int tid = threadIdx.x, lane = tid & 63, wid = tid >> 6;
  float v[16];
  float m = -1e30f;
#pragma unroll
  for (int i = 0; i < 4; ++i) {
    float4 x = *reinterpret_cast<const float4*>(rp + i * 1024 + tid * 4);
    v[i * 4 + 0] = x.x; v[i * 4 + 1] = x.y; v[i * 4 + 2] = x.z; v[i * 4 + 3] = x.w;
    m = fmaxf(m, fmaxf(fmaxf(x.x, x.y), fmaxf(x.z, x.w)));
  }
#pragma unroll
  for (int off = 32; off; off >>= 1) m = fmaxf(m, __shfl_xor(m, off));
  __shared__ float redm[4], reds[4];
  if (lane == 0) redm[wid] = m;
  __syncthreads();
  m = fmaxf(fmaxf(redm[0], redm[1]), fmaxf(redm[2], redm[3]));
  float sum = 0.f;
#pragma unroll
  for (int i = 0; i < 16; ++i) { v[i] = __expf(v[i] - m); sum += v[i]; }
#pragma unroll
  for (int off = 32; off; off >>= 1) sum += __shfl_xor(sum, off);
  if (lane == 0) reds[wid] = sum;
  __syncthreads();
  float inv = 1.0f / (reds[0] + reds[1] + reds[2] + reds[3]);
#pragma unroll
  for (int i = 0; i < 4; ++i) {
    float4 x;
    x.x = v[i * 4 + 0] * inv; x.y = v[i * 4 + 1] * inv;
    x.z = v[i * 4 + 2] * inv; x.w = v[i * 4 + 3] * inv;
    *reinterpret_cast<float4*>(rp + i * 1024 + tid * 4) = x;
  }
}

// ---------------- PV v5: 256(t) x 256(o), 512 thr, 8 waves, BK=64, dbuf, T14 A-split ----
// Structure clone of logits_v3: 64 MFMA/wave/iter, granule-involution LDS for both ops.
__global__ __launch_bounds__(512)
void pv_v5(const float* __restrict__ attn, const unsigned short* __restrict__ vT,
           float* __restrict__ out)
{
  __shared__ unsigned short lds[8][8192];   // [dbuf*4: A_s0,A_s1,B_s0,B_s1][16KB] = 128KB
  const int tid = threadIdx.x, lane = tid & 63, wid = tid >> 6;

  int bid = blockIdx.x;                     // 256 blocks
  int swz = (bid & 7) * 32 + (bid >> 3);    // bijective XCD swizzle
  const int b = swz >> 6, rem = swz & 63;
  const int t0 = (rem >> 2) * 256;          // 16 t-tiles
  const int n0 = (rem & 3) * 256;           // 4 o-tiles (consecutive blocks share t0 -> L2 reuse)
  const float* aB = attn + ((size_t)b * SS + t0) * SS;
  const unsigned short* vB = vT + ((size_t)b * DD + n0) * SS;

  const int sfr = (tid >> 2) & 15;
  const int scc = (tid & 3) ^ ((sfr >> 1) & 3);
  const int srowl = (tid >> 6) * 16 + sfr;
  const size_t row0 = (size_t)srowl * SS;
  const size_t row1 = (size_t)(srowl + 128) * SS;
  const int l0s = tid * 8, l1s = 4096 + tid * 8;

  const int wr = wid >> 2, wc = wid & 3;    // wave tile 128(t) x 64(o)
  const int rfr = lane & 15, rcc = lane >> 4;
  const int lp8 = (rfr * 4 + (rcc ^ ((rfr >> 1) & 3))) * 8;

  f32x4 acc[8][4] = {};
  float4 ar[8];   // A prefetch: [s0h0,s0h0+4, s0h1,.., s1h0,.., s1h1,..]

#define PV5_BLOAD(buf, k0) do { \
    gload16(vB + row0 + (k0) + scc * 8,      &lds[(buf)*4+2][l0s]); \
    gload16(vB + row1 + (k0) + scc * 8,      &lds[(buf)*4+2][l1s]); \
    gload16(vB + row0 + (k0) + 32 + scc * 8, &lds[(buf)*4+3][l0s]); \
    gload16(vB + row1 + (k0) + 32 + scc * 8, &lds[(buf)*4+3][l1s]); \
  } while (0)

#define PV5_ALOAD(k0) do { \
    ar[0] = *reinterpret_cast<const float4*>(aB + row0 + (k0) + scc * 8); \
    ar[1] = *reinterpret_cast<const float4*>(aB + row0 + (k0) + scc * 8 + 4); \
    ar[2] = *reinterpret_cast<const float4*>(aB + row1 + (k0) + scc * 8); \
    ar[3] = *reinterpret_cast<const float4*>(aB + row1 + (k0) + scc * 8 + 4); \
    ar[4] = *reinterpret_cast<const float4*>(aB + row0 + (k0) + 32 + scc * 8); \
    ar[5] = *reinterpret_cast<const float4*>(aB + row0 + (k0) + 32 + scc * 8 + 4); \
    ar[6] = *reinterpret_cast<const float4*>(aB + row1 + (k0) + 32 + scc * 8); \
    ar[7] = *reinterpret_cast<const float4*>(aB + row1 + (k0) + 32 + scc * 8 + 4); \
  } while (0)

#define PV5_AWRITE(buf) do { \
    _Pragma("unroll") \
    for (int p = 0; p < 4; ++p) { \
      int s = p >> 1, hh = p & 1; \
      ushort4 u0, u1; \
      u0.x = f2h(ar[p*2].x);   u0.y = f2h(ar[p*2].y); \
      u0.z = f2h(ar[p*2].z);   u0.w = f2h(ar[p*2].w); \
      u1.x = f2h(ar[p*2+1].x); u1.y = f2h(ar[p*2+1].y); \
      u1.z = f2h(ar[p*2+1].z); u1.w = f2h(ar[p*2+1].w); \
      unsigned short* d = &lds[(buf)*4 + s][(hh ? l1s : l0s)]; \
      *reinterpret_cast<ushort4*>(d)     = u0; \
      *reinterpret_cast<ushort4*>(d + 4) = u1; \
    } \
  } while (0)

  int cur = 0;
  PV5_BLOAD(0, 0);
  PV5_ALOAD(0);
  PV5_AWRITE(0);
  __syncthreads();

  for (int it = 0; it < 64; ++it) {
    if (it < 63) { PV5_BLOAD(cur ^ 1, (it + 1) * 64); PV5_ALOAD((it + 1) * 64); }

#pragma unroll
    for (int s = 0; s < 2; ++s) {
      f16x8 bf[4];
#pragma unroll
      for (int n = 0; n < 4; ++n)
        bf[n] = *reinterpret_cast<const f16x8*>(&lds[cur * 4 + 2 + s][(wc * 4 + n) * 512 + lp8]);
#pragma unroll
      for (int h = 0; h < 2; ++h) {
        f16x8 af[4];
#pragma unroll
        for (int m = 0; m < 4; ++m)
          af[m] = *reinterpret_cast<const f16x8*>(&lds[cur * 4 + s][(wr * 8 + h * 4 + m) * 512 + lp8]);
        __builtin_amdgcn_s_setprio(1);
#pragma unroll
        for (int m = 0; m < 4; ++m)
#pragma unroll
          for (int n = 0; n < 4; ++n)
            acc[h * 4 + m][n] = __builtin_amdgcn_mfma_f32_16x16x32_f16(af[m], bf[n], acc[h * 4 + m][n], 0, 0, 0);
        __builtin_amdgcn_s_setprio(0);
      }
    }

    if (it < 63) PV5_AWRITE(cur ^ 1);
    __syncthreads();
    cur ^= 1;
  }
#undef PV5_BLOAD
#undef PV5_ALOAD
#undef PV5_AWRITE

  const int col = lane & 15, rb = (lane >> 4) * 4;
#pragma unroll
  for (int m = 0; m < 8; ++m)
#pragma unroll
    for (int n = 0; n < 4; ++n) {
      int o = n0 + wc * 64 + n * 16 + col;
#pragma unroll
      for (int q = 0; q < 4; ++q) {
        int t = t0 + wr * 128 + m * 16 + rb + q;
        out[((size_t)b * SS + t) * DD + o] = acc[m][n][q];
      }
    }
}

extern "C" void kernel_launch(void* const* d_in, const int* in_sizes, int n_in,
                              void* d_out, int out_size, void* d_ws, size_t ws_size,
                              hipStream_t stream) {
  const float* query = (const float*)d_in[0];
  const float* key   = (const float*)d_in[1];
  const float* value = (const float*)d_in[2];
  const float* W     = (const float*)d_in[3];
  const float* bias  = (const float*)d_in[4];

  float* out  = (float*)d_out;                  // [B,S,D]
  float* attn = out + (size_t)BD * SS * DD;     // [B,S,S]

  // workspace (shorts): Whf,Wlf 2x2MB + xq(=vT),xk,xv,qfb,khi,klo 6x33.5MB ~= 205MB
  unsigned short* Whf = (unsigned short*)d_ws;
  unsigned short* Wlf = Whf + (size_t)DD * DD;
  unsigned short* xq  = Wlf + (size_t)DD * DD;   // aliased: vT reuses xq after proj_q
  unsigned short* xk  = xq  + (size_t)RTOT * DD;
  unsigned short* xv  = xk  + (size_t)RTOT * DD;
  unsigned short* qfb = xv  + (size_t)RTOT * DD;
  unsigned short* khi = qfb + (size_t)RTOT * DD;
  unsigned short* klo = khi + (size_t)RTOT * DD;
  unsigned short* vT  = xq;                       // alias (xq dead after proj_q)

  convx_kernel<<<dim3(2048, 1, 3), 256, 0, stream>>>(query, key, value, xq, xk, xv);
  split_w_kernel<<<DD * DD / (256 * 4), 256, 0, stream>>>(W, Whf, Wlf);

  dim3 gp(RTOT / 256, DD / 256);
  proj_one<2, 0><<<gp, 512, 0, stream>>>(xq, Whf, Wlf, bias, qfb, nullptr);
  proj_one<2, 1><<<gp, 512, 0, stream>>>(xk, Whf, Wlf, bias, khi, klo);
  proj_one<1, 2><<<gp, 512, 0, stream>>>(xv, Whf, nullptr, bias, vT, nullptr);

  logits_v3<<<(SS / 256) * (SS / 256) * BD, 512, 0, stream>>>(qfb, khi, klo, attn);
  softmax_kernel<<<RTOT, 256, 0, stream>>>(attn);
  pv_v5<<<(SS / 256) * (DD / 256) * BD, 512, 0, stream>>>(attn, vT, out);
}

// Round 11
// 698.872 us; speedup vs baseline: 1.5384x; 1.0509x over previous
//
#include <hip/hip_runtime.h>
#include <hip/hip_bf16.h>
#include <hip/hip_fp16.h>

#define BD 4
#define SS 4096
#define DD 1024
#define RTOT (BD*SS)   // 16384 total rows

typedef _Float16 f16;
typedef __attribute__((ext_vector_type(8))) _Float16 f16x8;
typedef __attribute__((ext_vector_type(4))) float f32x4;

static __device__ __forceinline__ unsigned short f2h(float f) {
  f16 h = (f16)f;
  return __builtin_bit_cast(unsigned short, h);
}
static __device__ __forceinline__ float h2f(unsigned short u) {
  return (float)__builtin_bit_cast(f16, u);
}

// async global->LDS, 16B/lane, wave-uniform LDS base + lane*16
static __device__ __forceinline__ void gload16(const void* g, void* l) {
  __builtin_amdgcn_global_load_lds(
      (const __attribute__((address_space(1))) unsigned int*)g,
      (__attribute__((address_space(3))) unsigned int*)l, 16, 0, 0);
}

// ---------------- split W into hi/lo f16 ----------------
__global__ void split_w_kernel(const float* __restrict__ W,
                               unsigned short* __restrict__ Wh,
                               unsigned short* __restrict__ Wl) {
  int i = (blockIdx.x * 256 + threadIdx.x) * 4;
  float4 x = *reinterpret_cast<const float4*>(W + i);
  ushort4 h, l;
  h.x = f2h(x.x); l.x = f2h(x.x - h2f(h.x));
  h.y = f2h(x.y); l.y = f2h(x.y - h2f(h.y));
  h.z = f2h(x.z); l.z = f2h(x.z - h2f(h.z));
  h.w = f2h(x.w); l.w = f2h(x.w - h2f(h.w));
  *reinterpret_cast<ushort4*>(Wh + i) = h;
  *reinterpret_cast<ushort4*>(Wl + i) = l;
}

// ---------------- unified projection: 256x256 tile, 512 thr, fused fp32->f16 A ----------
// TERMS: 1 (v: X*Wh) or 2 (q/k: X*Wh + X*Wl)
// EPI: 0 = f16 single row-major; 1 = f16 hi/lo row-major; 2 = vT [b][o][s]
// A-path: T14 reg-stage (fp32 loads with prefetch, cvt+ds_write after MFMA) — pv_v5 pattern.
template<int TERMS, int EPI>
__global__ __launch_bounds__(512, 2)
void proj_one(const float* __restrict__ X,
              const unsigned short* __restrict__ Wh,
              const unsigned short* __restrict__ Wl,
              const float* __restrict__ bias,
              unsigned short* __restrict__ O1, unsigned short* __restrict__ O2)
{
  constexpr int OPS = 1 + TERMS;
  __shared__ unsigned short lds[2 * OPS][8192];
  const int tid = threadIdx.x, lane = tid & 63, wid = tid >> 6;
  const int t0 = blockIdx.x * 256;   // row tile
  const int n0 = blockIdx.y * 256;   // output-col tile

  const int sfr = (tid >> 2) & 15;
  const int scc = (tid & 3) ^ ((sfr >> 1) & 3);
  const int srowl = (tid >> 6) * 16 + sfr;
  const size_t arow0 = (size_t)(t0 + srowl) * DD;          // fp32 A rows
  const size_t arow1 = (size_t)(t0 + srowl + 128) * DD;
  const size_t boff  = (size_t)(n0 + srowl) * DD + scc * 8;
  const int l0s = tid * 8;
  const int l1s = 4096 + tid * 8;   // +128 rows

  float4 ar[4];

#define PBLOAD(cur, k0)  do { \
    gload16(Wh + boff + (k0),          &lds[(cur)*OPS+1][l0s]); \
    gload16(Wh + boff + 131072 + (k0), &lds[(cur)*OPS+1][l1s]); \
    if (TERMS == 2) { \
      gload16(Wl + boff + (k0),          &lds[(cur)*OPS+2][l0s]); \
      gload16(Wl + boff + 131072 + (k0), &lds[(cur)*OPS+2][l1s]); \
    } \
  } while (0)

#define PALOAD(k0) do { \
    ar[0] = *reinterpret_cast<const float4*>(X + arow0 + (k0) + scc * 8); \
    ar[1] = *reinterpret_cast<const float4*>(X + arow0 + (k0) + scc * 8 + 4); \
    ar[2] = *reinterpret_cast<const float4*>(X + arow1 + (k0) + scc * 8); \
    ar[3] = *reinterpret_cast<const float4*>(X + arow1 + (k0) + scc * 8 + 4); \
  } while (0)

#define PAWRITE(buf) do { \
    ushort4 u0, u1, u2, u3; \
    u0.x = f2h(ar[0].x); u0.y = f2h(ar[0].y); u0.z = f2h(ar[0].z); u0.w = f2h(ar[0].w); \
    u1.x = f2h(ar[1].x); u1.y = f2h(ar[1].y); u1.z = f2h(ar[1].z); u1.w = f2h(ar[1].w); \
    u2.x = f2h(ar[2].x); u2.y = f2h(ar[2].y); u2.z = f2h(ar[2].z); u2.w = f2h(ar[2].w); \
    u3.x = f2h(ar[3].x); u3.y = f2h(ar[3].y); u3.z = f2h(ar[3].z); u3.w = f2h(ar[3].w); \
    unsigned short* d0 = &lds[(buf)*OPS+0][l0s]; \
    *reinterpret_cast<ushort4*>(d0)     = u0; \
    *reinterpret_cast<ushort4*>(d0 + 4) = u1; \
    unsigned short* d1 = &lds[(buf)*OPS+0][l1s]; \
    *reinterpret_cast<ushort4*>(d1)     = u2; \
    *reinterpret_cast<ushort4*>(d1 + 4) = u3; \
  } while (0)

  const int wr = wid >> 2, wc = wid & 3;   // wave tile 128(row) x 64(col)
  const int rfr = lane & 15, rcc = lane >> 4;
  const int lp8 = (rfr * 4 + (rcc ^ ((rfr >> 1) & 3))) * 8;

  f32x4 acc[8][4] = {};

  int cur = 0;
  PBLOAD(0, 0);
  PALOAD(0);
  PAWRITE(0);
  __syncthreads();

  for (int t = 0; t < 32; ++t) {
    if (t < 31) { PBLOAD(cur ^ 1, (t + 1) * 32); PALOAD((t + 1) * 32); }

    f16x8 bhf[4], blf[4];
#pragma unroll
    for (int n = 0; n < 4; ++n) {
      bhf[n] = *reinterpret_cast<const f16x8*>(&lds[cur * OPS + 1][(wc * 4 + n) * 512 + lp8]);
      if (TERMS == 2)
        blf[n] = *reinterpret_cast<const f16x8*>(&lds[cur * OPS + 2][(wc * 4 + n) * 512 + lp8]);
    }
#pragma unroll
    for (int h = 0; h < 2; ++h) {
      f16x8 ahf[4];
#pragma unroll
      for (int m = 0; m < 4; ++m)
        ahf[m] = *reinterpret_cast<const f16x8*>(&lds[cur * OPS + 0][(wr * 8 + h * 4 + m) * 512 + lp8]);
      __builtin_amdgcn_s_setprio(1);
#pragma unroll
      for (int m = 0; m < 4; ++m)
#pragma unroll
        for (int n = 0; n < 4; ++n) {
          acc[h * 4 + m][n] = __builtin_amdgcn_mfma_f32_16x16x32_f16(ahf[m], bhf[n], acc[h * 4 + m][n], 0, 0, 0);
          if (TERMS == 2)
            acc[h * 4 + m][n] = __builtin_amdgcn_mfma_f32_16x16x32_f16(ahf[m], blf[n], acc[h * 4 + m][n], 0, 0, 0);
        }
      __builtin_amdgcn_s_setprio(0);
    }

    if (t < 31) PAWRITE(cur ^ 1);
    __syncthreads();
    cur ^= 1;
  }
#undef PBLOAD
#undef PALOAD
#undef PAWRITE

  const int col = lane & 15, rb = (lane >> 4) * 4;
#pragma unroll
  for (int m = 0; m < 8; ++m)
#pragma unroll
    for (int n = 0; n < 4; ++n) {
      int oc = n0 + wc * 64 + n * 16 + col;
      float bv = bias[oc];
      if (EPI == 2) {
        int tr = t0 + wr * 128 + m * 16 + rb;      // 4 consecutive rows
        int bb = tr >> 12, s = tr & (SS - 1);
        ushort4 h;
        h.x = f2h(acc[m][n][0] + bv);
        h.y = f2h(acc[m][n][1] + bv);
        h.z = f2h(acc[m][n][2] + bv);
        h.w = f2h(acc[m][n][3] + bv);
        *reinterpret_cast<ushort4*>(O1 + ((size_t)(bb * DD + oc)) * SS + s) = h;
      } else {
#pragma unroll
        for (int q = 0; q < 4; ++q) {
          int tr = t0 + wr * 128 + m * 16 + rb + q;
          float p = acc[m][n][q] + bv;
          if (EPI == 0) {
            O1[(size_t)tr * DD + oc] = f2h(p);
          } else {
            unsigned short h = f2h(p);
            O1[(size_t)tr * DD + oc] = h;
            O2[(size_t)tr * DD + oc] = f2h(p - h2f(h));
          }
        }
      }
    }
}

// ---------------- logits v3: 2-term asymmetric f16 (qf single, k hi/lo) ----------------
__global__ __launch_bounds__(512, 2)
void logits_v3(const unsigned short* __restrict__ qf,
               const unsigned short* __restrict__ kh, const unsigned short* __restrict__ kl,
               float* __restrict__ out)
{
  __shared__ unsigned short lds[6][8192];   // [dbuf*3 ops][16KB each]
  const int tid = threadIdx.x, lane = tid & 63, wid = tid >> 6;

  int bid = blockIdx.x;
  int swz = (bid & 7) * 128 + (bid >> 3);
  const int b = swz >> 8;
  const int r = swz & 255;
  const int t0 = (r >> 4) * 256, s0 = (r & 15) * 256;

  const unsigned short* qB  = qf + (size_t)b * SS * DD;
  const unsigned short* khB = kh + (size_t)b * SS * DD;
  const unsigned short* klB = kl + (size_t)b * SS * DD;

  const int sfr = (tid >> 2) & 15;
  const int scc = (tid & 3) ^ ((sfr >> 1) & 3);
  const int srowl = (tid >> 6) * 16 + sfr;
  const size_t qoff0 = (size_t)(t0 + srowl) * DD + scc * 8;
  const size_t koff0 = (size_t)(s0 + srowl) * DD + scc * 8;
  const int l0s = tid * 8;
  const int l1s = 4096 + tid * 8;

#define STAGE(cur, k0)  do { \
    gload16(qB  + qoff0 + (k0),          &lds[(cur)*3+0][l0s]); \
    gload16(qB  + qoff0 + 131072 + (k0), &lds[(cur)*3+0][l1s]); \
    gload16(khB + koff0 + (k0),          &lds[(cur)*3+1][l0s]); \
    gload16(khB + koff0 + 131072 + (k0), &lds[(cur)*3+1][l1s]); \
    gload16(klB + koff0 + (k0),          &lds[(cur)*3+2][l0s]); \
    gload16(klB + koff0 + 131072 + (k0), &lds[(cur)*3+2][l1s]); \
  } while (0)

  const int wr = wid >> 2, wc = wid & 3;
  const int rfr = lane & 15, rcc = lane >> 4;
  const int lp8 = (rfr * 4 + (rcc ^ ((rfr >> 1) & 3))) * 8;

  f32x4 acc[8][4] = {};

  int cur = 0;
  STAGE(0, 0);
  __syncthreads();

  for (int t = 0; t < 32; ++t) {
    if (t < 31) STAGE(cur ^ 1, (t + 1) * 32);

    f16x8 bhf[4], blf[4];
#pragma unroll
    for (int n = 0; n < 4; ++n) {
      bhf[n] = *reinterpret_cast<const f16x8*>(&lds[cur * 3 + 1][(wc * 4 + n) * 512 + lp8]);
      blf[n] = *reinterpret_cast<const f16x8*>(&lds[cur * 3 + 2][(wc * 4 + n) * 512 + lp8]);
    }
#pragma unroll
    for (int h = 0; h < 2; ++h) {
      f16x8 ahf[4];
#pragma unroll
      for (int m = 0; m < 4; ++m)
        ahf[m] = *reinterpret_cast<const f16x8*>(&lds[cur * 3 + 0][(wr * 8 + h * 4 + m) * 512 + lp8]);
      __builtin_amdgcn_s_setprio(1);
#pragma unroll
      for (int m = 0; m < 4; ++m)
#pragma unroll
        for (int n = 0; n < 4; ++n) {
          acc[h * 4 + m][n] = __builtin_amdgcn_mfma_f32_16x16x32_f16(ahf[m], bhf[n], acc[h * 4 + m][n], 0, 0, 0);
          acc[h * 4 + m][n] = __builtin_amdgcn_mfma_f32_16x16x32_f16(ahf[m], blf[n], acc[h * 4 + m][n], 0, 0, 0);
        }
      __builtin_amdgcn_s_setprio(0);
    }
    __syncthreads();
    cur ^= 1;
  }
#undef STAGE

  const int col = lane & 15, rb = (lane >> 4) * 4;
#pragma unroll
  for (int m = 0; m < 8; ++m)
#pragma unroll
    for (int n = 0; n < 4; ++n) {
      int s = s0 + wc * 64 + n * 16 + col;
#pragma unroll
      for (int q = 0; q < 4; ++q) {
        int tr = t0 + wr * 128 + m * 16 + rb + q;
        out[((size_t)b * SS + tr) * SS + s] = acc[m][n][q];
      }
    }
}

// ---------------- row softmax in-place ----------------
__global__ __launch_bounds__(256)
void softmax_kernel(float* __restrict__ attn) {
  float* rp = attn + (size_t)blockIdx.x * SS;
  const int tid = threadIdx.x, lane = tid & 63, wid = tid >> 6;
  float v[16];
  float m = -1e30f;
#pragma unroll
  for (int i = 0; i < 4; ++i) {
    float4 x = *reinterpret_cast<const float4*>(rp + i * 1024 + tid * 4);
    v[i * 4 + 0] = x.x; v[i * 4 + 1] = x.y; v[i * 4 + 2] = x.z; v[i * 4 + 3] = x.w;
    m = fmaxf(m, fmaxf(fmaxf(x.x, x.y), fmaxf(x.z, x.w)));
  }
#pragma unroll
  for (int off = 32; off; off >>= 1) m = fmaxf(m, __shfl_xor(m, off));
  __shared__ float redm[4], reds[4];
  if (lane == 0) redm[wid] = m;
  __syncthreads();
  m = fmaxf(fmaxf(redm[0], redm[1]), fmaxf(redm[2], redm[3]));
  float sum = 0.f;
#pragma unroll
  for (int i = 0; i < 16; ++i) { v[i] = __expf(v[i] - m); sum += v[i]; }
#pragma unroll
  for (int off = 32; off; off >>= 1) sum += __shfl_xor(sum, off);
  if (lane == 0) reds[wid] = sum;
  __syncthreads();
  float inv = 1.0f / (reds[0] + reds[1] + reds[2] + reds[3]);
#pragma unroll
  for (int i = 0; i < 4; ++i) {
    float4 x;
    x.x = v[i * 4 + 0] * inv; x.y = v[i * 4 + 1] * inv;
    x.z = v[i * 4 + 2] * inv; x.w = v[i * 4 + 3] * inv;
    *reinterpret_cast<float4*>(rp + i * 1024 + tid * 4) = x;
  }
}

// ---------------- PV v5: 256(t) x 256(o), 512 thr, 8 waves, BK=64, dbuf, T14 A-split ----
__global__ __launch_bounds__(512)
void pv_v5(const float* __restrict__ attn, const unsigned short* __restrict__ vT,
           float* __restrict__ out)
{
  __shared__ unsigned short lds[8][8192];   // [dbuf*4: A_s0,A_s1,B_s0,B_s1][16KB] = 128KB
  const int tid = threadIdx.x, lane = tid & 63, wid = tid >> 6;

  int bid = blockIdx.x;                     // 256 blocks
  int swz = (bid & 7) * 32 + (bid >> 3);    // bijective XCD swizzle
  const int b = swz >> 6, rem = swz & 63;
  const int t0 = (rem >> 2) * 256;          // 16 t-tiles
  const int n0 = (rem & 3) * 256;           // 4 o-tiles
  const float* aB = attn + ((size_t)b * SS + t0) * SS;
  const unsigned short* vB = vT + ((size_t)b * DD + n0) * SS;

  const int sfr = (tid >> 2) & 15;
  const int scc = (tid & 3) ^ ((sfr >> 1) & 3);
  const int srowl = (tid >> 6) * 16 + sfr;
  const size_t row0 = (size_t)srowl * SS;
  const size_t row1 = (size_t)(srowl + 128) * SS;
  const int l0s = tid * 8, l1s = 4096 + tid * 8;

  const int wr = wid >> 2, wc = wid & 3;    // wave tile 128(t) x 64(o)
  const int rfr = lane & 15, rcc = lane >> 4;
  const int lp8 = (rfr * 4 + (rcc ^ ((rfr >> 1) & 3))) * 8;

  f32x4 acc[8][4] = {};
  float4 ar[8];

#define PV5_BLOAD(buf, k0) do { \
    gload16(vB + row0 + (k0) + scc * 8,      &lds[(buf)*4+2][l0s]); \
    gload16(vB + row1 + (k0) + scc * 8,      &lds[(buf)*4+2][l1s]); \
    gload16(vB + row0 + (k0) + 32 + scc * 8, &lds[(buf)*4+3][l0s]); \
    gload16(vB + row1 + (k0) + 32 + scc * 8, &lds[(buf)*4+3][l1s]); \
  } while (0)

#define PV5_ALOAD(k0) do { \
    ar[0] = *reinterpret_cast<const float4*>(aB + row0 + (k0) + scc * 8); \
    ar[1] = *reinterpret_cast<const float4*>(aB + row0 + (k0) + scc * 8 + 4); \
    ar[2] = *reinterpret_cast<const float4*>(aB + row1 + (k0) + scc * 8); \
    ar[3] = *reinterpret_cast<const float4*>(aB + row1 + (k0) + scc * 8 + 4); \
    ar[4] = *reinterpret_cast<const float4*>(aB + row0 + (k0) + 32 + scc * 8); \
    ar[5] = *reinterpret_cast<const float4*>(aB + row0 + (k0) + 32 + scc * 8 + 4); \
    ar[6] = *reinterpret_cast<const float4*>(aB + row1 + (k0) + 32 + scc * 8); \
    ar[7] = *reinterpret_cast<const float4*>(aB + row1 + (k0) + 32 + scc * 8 + 4); \
  } while (0)

#define PV5_AWRITE(buf) do { \
    _Pragma("unroll") \
    for (int p = 0; p < 4; ++p) { \
      int s = p >> 1, hh = p & 1; \
      ushort4 u0, u1; \
      u0.x = f2h(ar[p*2].x);   u0.y = f2h(ar[p*2].y); \
      u0.z = f2h(ar[p*2].z);   u0.w = f2h(ar[p*2].w); \
      u1.x = f2h(ar[p*2+1].x); u1.y = f2h(ar[p*2+1].y); \
      u1.z = f2h(ar[p*2+1].z); u1.w = f2h(ar[p*2+1].w); \
      unsigned short* d = &lds[(buf)*4 + s][(hh ? l1s : l0s)]; \
      *reinterpret_cast<ushort4*>(d)     = u0; \
      *reinterpret_cast<ushort4*>(d + 4) = u1; \
    } \
  } while (0)

  int cur = 0;
  PV5_BLOAD(0, 0);
  PV5_ALOAD(0);
  PV5_AWRITE(0);
  __syncthreads();

  for (int it = 0; it < 64; ++it) {
    if (it < 63) { PV5_BLOAD(cur ^ 1, (it + 1) * 64); PV5_ALOAD((it + 1) * 64); }

#pragma unroll
    for (int s = 0; s < 2; ++s) {
      f16x8 bf[4];
#pragma unroll
      for (int n = 0; n < 4; ++n)
        bf[n] = *reinterpret_cast<const f16x8*>(&lds[cur * 4 + 2 + s][(wc * 4 + n) * 512 + lp8]);
#pragma unroll
      for (int h = 0; h < 2; ++h) {
        f16x8 af[4];
#pragma unroll
        for (int m = 0; m < 4; ++m)
          af[m] = *reinterpret_cast<const f16x8*>(&lds[cur * 4 + s][(wr * 8 + h * 4 + m) * 512 + lp8]);
        __builtin_amdgcn_s_setprio(1);
#pragma unroll
        for (int m = 0; m < 4; ++m)
#pragma unroll
          for (int n = 0; n < 4; ++n)
            acc[h * 4 + m][n] = __builtin_amdgcn_mfma_f32_16x16x32_f16(af[m], bf[n], acc[h * 4 + m][n], 0, 0, 0);
        __builtin_amdgcn_s_setprio(0);
      }
    }

    if (it < 63) PV5_AWRITE(cur ^ 1);
    __syncthreads();
    cur ^= 1;
  }
#undef PV5_BLOAD
#undef PV5_ALOAD
#undef PV5_AWRITE

  const int col = lane & 15, rb = (lane >> 4) * 4;
#pragma unroll
  for (int m = 0; m < 8; ++m)
#pragma unroll
    for (int n = 0; n < 4; ++n) {
      int o = n0 + wc * 64 + n * 16 + col;
#pragma unroll
      for (int q = 0; q < 4; ++q) {
        int t = t0 + wr * 128 + m * 16 + rb + q;
        out[((size_t)b * SS + t) * DD + o] = acc[m][n][q];
      }
    }
}

extern "C" void kernel_launch(void* const* d_in, const int* in_sizes, int n_in,
                              void* d_out, int out_size, void* d_ws, size_t ws_size,
                              hipStream_t stream) {
  const float* query = (const float*)d_in[0];
  const float* key   = (const float*)d_in[1];
  const float* value = (const float*)d_in[2];
  const float* W     = (const float*)d_in[3];
  const float* bias  = (const float*)d_in[4];

  float* out  = (float*)d_out;                  // [B,S,D]
  float* attn = out + (size_t)BD * SS * DD;     // [B,S,S]

  // workspace (shorts): Whf,Wlf 2x2MB + qfb,khi,klo,vT 4x33.5MB ~= 138MB
  unsigned short* Whf = (unsigned short*)d_ws;
  unsigned short* Wlf = Whf + (size_t)DD * DD;
  unsigned short* qfb = Wlf + (size_t)DD * DD;
  unsigned short* khi = qfb + (size_t)RTOT * DD;
  unsigned short* klo = khi + (size_t)RTOT * DD;
  unsigned short* vT  = klo + (size_t)RTOT * DD;

  split_w_kernel<<<DD * DD / (256 * 4), 256, 0, stream>>>(W, Whf, Wlf);

  dim3 gp(RTOT / 256, DD / 256);
  proj_one<2, 0><<<gp, 512, 0, stream>>>(query, Whf, Wlf, bias, qfb, nullptr);
  proj_one<2, 1><<<gp, 512, 0, stream>>>(key,   Whf, Wlf, bias, khi, klo);
  proj_one<1, 2><<<gp, 512, 0, stream>>>(value, Whf, nullptr, bias, vT, nullptr);

  logits_v3<<<(SS / 256) * (SS / 256) * BD, 512, 0, stream>>>(qfb, khi, klo, attn);
  softmax_kernel<<<RTOT, 256, 0, stream>>>(attn);
  pv_v5<<<(SS / 256) * (DD / 256) * BD, 512, 0, stream>>>(attn, vT, out);
}